// Round 12
// baseline (252.102 us; speedup 1.0000x reference)
//
#include <hip/hip_runtime.h>
#include <cstddef>
#include <cstring>

#define NN 50000
#define NNP 50048
#define NE 800000
#define D 128
#define NG 512
#define BN_EPS 1e-5f
#define RSZC 25000    // count: nodes per range (2 ranges, 100 KB dyn LDS)
#define RSZF 12500    // fill: nodes per range (4 ranges, 50 KB LDS)
#define NCHUNK 64
#define CSZ 12500     // edges per chunk
#define EDGE_BLOCKS 256

typedef __bf16 bf16_t;
typedef __bf16 bf16x8 __attribute__((ext_vector_type(8)));
typedef float f32x4 __attribute__((ext_vector_type(4)));

// ---- workspace layout (float offsets) ----
#define OFF_ACCN 0            // float[4*512]
#define OFF_ACCE 2048         // float[4*512]
#define OFF_CTR  4096         // int[1]
#define OFF_CTR2 4104         // int[1]
#define ZERO_FLOATS 4160      // zeroed region = [0, here)
#define OFF_DIS  4160         // float[50048]
#define OFF_CNT  54208        // int[50048]
#define OFF_COLP 104256      // int[50048]
#define OFF_ENDS 154304      // int[50048]
#define OFF_BSUM 204352      // int[256]
#define OFF_BP   304896      // float[3*128 padded]
#define OFF_WPT  305408      // bf16[3*128*128] (24576 floats)
#define OFF_PR   329984      // int[64][50048] = 3203072
#define OFF_PC   3533056     // int[64][50048] = 3203072 (CPS after csr_mid)
#define OFF_SRCS OFF_PR      // uint[800000], aliases PR (dead after csr_mid_scan)
#define OFF_TB   1129984     // float4[50048] = 200192 floats, after srcs in PR region
#define OFF_HBFA 7536128     // bf16[50048*128] (3203072 floats)
#define OFF_HBFB 10739200    // bf16[50048*128]

// ---- output layout (float offsets in d_out) ----
#define O_NKEY 0
#define O_EKEY 50000
#define O_NKN  850000
#define O_NEN  850512
#define O_EKN  851024
#define O_EEN  851536
#define O_NZN  852048
#define O_NZE  852560

__device__ __forceinline__ float sigmoidf(float x) {
    return 1.0f / (1.0f + expf(-x));
}

__device__ __forceinline__ unsigned short f2bf_bits(float f) {
    bf16_t h = (bf16_t)f;
    unsigned short u;
    __builtin_memcpy(&u, &h, 2);
    return u;
}

__device__ __forceinline__ float bf_lo(unsigned int u) {
    return __uint_as_float(u << 16);
}
__device__ __forceinline__ float bf_hi(unsigned int u) {
    return __uint_as_float(u & 0xFFFF0000u);
}

// count histograms (2 node ranges x 64 chunks x 2 dirs) + prep_w rides on z==2.
__global__ __launch_bounds__(256) void count_prep(const int* __restrict__ ei,
                                                  int* __restrict__ PR,
                                                  int* __restrict__ PC,
                                                  const float* __restrict__ W,
                                                  const float* __restrict__ gamma,
                                                  const float* __restrict__ beta,
                                                  const float* __restrict__ mean,
                                                  const float* __restrict__ var,
                                                  bf16_t* __restrict__ Wpt,
                                                  float* __restrict__ bp) {
    const int tid = threadIdx.x;
    if (blockIdx.z == 2) {
        if (blockIdx.x == 0 && blockIdx.y < 3 && tid < D) {
            int l = blockIdx.y;
            int j = tid;
            float acc = 0.f;
            for (int k = 0; k < D; ++k) {
                float a = gamma[l * D + k] * rsqrtf(var[l * D + k] + BN_EPS);
                float c = beta[l * D + k] - mean[l * D + k] * a;
                float w = W[l * D * D + k * D + j];
                Wpt[l * D * D + j * D + k] = (bf16_t)(a * w);
                acc = fmaf(c, w, acc);
            }
            bp[l * D + j] = acc;
        }
        return;
    }
    extern __shared__ int hist[];
    const int r = blockIdx.x, p = blockIdx.y, dirz = blockIdx.z;
    for (int i = tid; i < RSZC; i += 256) hist[i] = 0;
    __syncthreads();
    const int base = r * RSZC;
    const int4* ids = (const int4*)(ei + dirz * NE + p * CSZ);
    for (int i = tid; i < CSZ / 4; i += 256) {
        int4 v = ids[i];
        int d0 = v.x - base, d1 = v.y - base, d2 = v.z - base, d3 = v.w - base;
        if ((unsigned)d0 < RSZC) atomicAdd(&hist[d0], 1);
        if ((unsigned)d1 < RSZC) atomicAdd(&hist[d1], 1);
        if ((unsigned)d2 < RSZC) atomicAdd(&hist[d2], 1);
        if ((unsigned)d3 < RSZC) atomicAdd(&hist[d3], 1);
    }
    __syncthreads();
    int* dst = (dirz == 0 ? PR : PC) + p * NNP + base;
    for (int i = tid; i < RSZC; i += 256) dst[i] = hist[i];
}

// merged csr_mid + scan3 with a device-scope barrier (196 blocks < 256 CUs,
// all co-resident -> spin is deadlock-free).
__global__ void csr_mid_scan(const int* __restrict__ PR, int* __restrict__ PC,
                             float* __restrict__ dis, int* __restrict__ cnt,
                             int* __restrict__ colp, int* __restrict__ bsum,
                             int* __restrict__ ends, int* __restrict__ ctr2) {
    __shared__ int s[256];
    const int t = threadIdx.x;
    const int i = blockIdx.x * 256 + t;
    int run = 0;
    if (i < NN) {
        int dg = 0;
#pragma unroll 8
        for (int k = 0; k < NCHUNK; ++k) dg += PR[k * NNP + i];
        dis[i] = rsqrtf((float)(dg + 1));
        for (int k = 0; k < NCHUNK; ++k) {
            int v = PC[k * NNP + i];
            PC[k * NNP + i] = run;
            run += v;
        }
        cnt[i] = run;
    }
    s[t] = run;
    __syncthreads();
    for (int o = 1; o < 256; o <<= 1) {
        int add = (t >= o) ? s[t - o] : 0;
        __syncthreads();
        s[t] += add;
        __syncthreads();
    }
    const int local_excl = s[t] - run;
    if (t == 255) {
        __hip_atomic_store(&bsum[blockIdx.x], s[255], __ATOMIC_RELEASE,
                           __HIP_MEMORY_SCOPE_AGENT);
        __hip_atomic_fetch_add(ctr2, 1, __ATOMIC_RELEASE, __HIP_MEMORY_SCOPE_AGENT);
    }
    if (t == 0) {
        while (__hip_atomic_load(ctr2, __ATOMIC_ACQUIRE, __HIP_MEMORY_SCOPE_AGENT) <
               (int)gridDim.x) {
            __builtin_amdgcn_s_sleep(8);
        }
    }
    __syncthreads();
    // phase 2: block offset = sum of bsum[0..bid-1]
    s[t] = (t < blockIdx.x)
               ? __hip_atomic_load(&bsum[t], __ATOMIC_ACQUIRE, __HIP_MEMORY_SCOPE_AGENT)
               : 0;
    __syncthreads();
    for (int o = 128; o; o >>= 1) {
        if (t < o) s[t] += s[t + o];
        __syncthreads();
    }
    const int boff = s[0];
    if (i < NN) {
        int v = local_excl + boff;
        colp[i] = v;
        ends[i] = v + run;
    }
}

// atomic-free(global) CSR fill; packed entries: src idx (lo16) | bf16 dis[src] (hi16)
__global__ __launch_bounds__(256) void fill_part(const int* __restrict__ ei,
                                                 const int* __restrict__ colp,
                                                 const int* __restrict__ CPS,
                                                 const float* __restrict__ dis,
                                                 unsigned int* __restrict__ srcs) {
    __shared__ int curs[RSZF];
    const int r = blockIdx.x, p = blockIdx.y;
    const int tid = threadIdx.x;
    const int base = r * RSZF;
    for (int i = tid; i < RSZF; i += 256)
        curs[i] = colp[base + i] + CPS[p * NNP + base + i];
    __syncthreads();
    const int4* rows = (const int4*)(ei + p * CSZ);
    const int4* cols = (const int4*)(ei + NE + p * CSZ);
    for (int i = tid; i < CSZ / 4; i += 256) {
        int4 rv = rows[i];
        int4 cv = cols[i];
        int d;
        d = cv.x - base;
        if ((unsigned)d < RSZF)
            srcs[atomicAdd(&curs[d], 1)] =
                (unsigned int)rv.x | ((unsigned int)f2bf_bits(dis[rv.x]) << 16);
        d = cv.y - base;
        if ((unsigned)d < RSZF)
            srcs[atomicAdd(&curs[d], 1)] =
                (unsigned int)rv.y | ((unsigned int)f2bf_bits(dis[rv.y]) << 16);
        d = cv.z - base;
        if ((unsigned)d < RSZF)
            srcs[atomicAdd(&curs[d], 1)] =
                (unsigned int)rv.z | ((unsigned int)f2bf_bits(dis[rv.z]) << 16);
        d = cv.w - base;
        if ((unsigned)d < RSZF)
            srcs[atomicAdd(&curs[d], 1)] =
                (unsigned int)rv.w | ((unsigned int)f2bf_bits(dis[rv.w]) << 16);
    }
}

// FUSED layers 0+1 with B0,B1 staged in LDS (XOR-swizzled 16B units).
__global__ __launch_bounds__(256) void gemm01(const float* __restrict__ X,
                                              const bf16_t* __restrict__ Bt0,
                                              const bf16_t* __restrict__ Bt1,
                                              const float* __restrict__ bias0,
                                              const float* __restrict__ bias1,
                                              bf16_t* __restrict__ out) {
    extern __shared__ __align__(16) unsigned short smem[];
    unsigned short* Bs0 = smem;             // 32 KB
    unsigned short* Bs1 = smem + 16384;     // 32 KB
    unsigned short* As  = smem + 32768;     // 16 KB
    const int tid = threadIdx.x;
    const int wv = tid >> 6;
    const int lane = tid & 63;
    const int l15 = lane & 15;
    const int l4 = lane >> 4;
    const int row0 = blockIdx.x * 64;

    for (int q = tid; q < 2048; q += 256) {
        int r = q >> 4, u = q & 15;
        int us = (u ^ (r & 7)) * 8;
        *(uint4*)&Bs0[r * 128 + us] = *(const uint4*)(Bt0 + r * D + u * 8);
        *(uint4*)&Bs1[r * 128 + us] = *(const uint4*)(Bt1 + r * D + u * 8);
    }

    bf16x8 afrag[4];
    {
        int r = row0 + wv * 16 + l15;
        int rc = (r < NN) ? r : (NN - 1);
#pragma unroll
        for (int kk = 0; kk < 4; ++kk) {
            int off = rc * D + kk * 32 + l4 * 8;
            float4 f0 = *(const float4*)(X + off);
            float4 f1 = *(const float4*)(X + off + 4);
            bf16x8 a;
            a[0] = (bf16_t)f0.x; a[1] = (bf16_t)f0.y;
            a[2] = (bf16_t)f0.z; a[3] = (bf16_t)f0.w;
            a[4] = (bf16_t)f1.x; a[5] = (bf16_t)f1.y;
            a[6] = (bf16_t)f1.z; a[7] = (bf16_t)f1.w;
            afrag[kk] = a;
        }
    }
    __syncthreads();

    const int rsw = l15 & 7;
    f32x4 acc[8];
#pragma unroll
    for (int n = 0; n < 8; ++n) acc[n] = (f32x4){0.f, 0.f, 0.f, 0.f};
#pragma unroll
    for (int n = 0; n < 8; ++n) {
#pragma unroll
        for (int kk = 0; kk < 4; ++kk) {
            bf16x8 bfrag = *(const bf16x8*)&Bs0[(n * 16 + l15) * 128 + ((kk * 4 + l4) ^ rsw) * 8];
            acc[n] = __builtin_amdgcn_mfma_f32_16x16x32_bf16(afrag[kk], bfrag, acc[n], 0, 0, 0);
        }
    }
#pragma unroll
    for (int n = 0; n < 8; ++n) {
        int col = n * 16 + l15;
        float bv = bias0[col];
#pragma unroll
        for (int r = 0; r < 4; ++r) {
            int rl = wv * 16 + l4 * 4 + r;
            float v = fmaxf(acc[n][r] + bv, 0.f);
            int cs = ((col >> 3) ^ (rl & 7));
            As[rl * 128 + cs * 8 + (col & 7)] = f2bf_bits(v);
        }
    }
    __syncthreads();

    const int rl = wv * 16 + l15;
    bf16x8 af2[4];
#pragma unroll
    for (int kk = 0; kk < 4; ++kk) {
        int cs = (kk * 4 + l4) ^ (rl & 7);
        af2[kk] = *(const bf16x8*)&As[rl * 128 + cs * 8];
    }
#pragma unroll
    for (int n = 0; n < 8; ++n) acc[n] = (f32x4){0.f, 0.f, 0.f, 0.f};
#pragma unroll
    for (int n = 0; n < 8; ++n) {
#pragma unroll
        for (int kk = 0; kk < 4; ++kk) {
            bf16x8 bfrag = *(const bf16x8*)&Bs1[(n * 16 + l15) * 128 + ((kk * 4 + l4) ^ rsw) * 8];
            acc[n] = __builtin_amdgcn_mfma_f32_16x16x32_bf16(af2[kk], bfrag, acc[n], 0, 0, 0);
        }
    }
#pragma unroll
    for (int n = 0; n < 8; ++n) {
        int col = n * 16 + l15;
        float bv = bias1[col];
#pragma unroll
        for (int r = 0; r < 4; ++r) {
            int row = row0 + wv * 16 + l4 * 4 + r;
            if (row < NN) out[(size_t)row * D + col] = (bf16_t)(acc[n][r] + bv);
        }
    }
}

// layer-2 GEMM with B staged in LDS
__global__ __launch_bounds__(256) void gemm2(const bf16_t* __restrict__ A,
                                             const bf16_t* __restrict__ Bt,
                                             const float* __restrict__ bias,
                                             bf16_t* __restrict__ out) {
    __shared__ __align__(16) unsigned short Bs[128 * 128];
    const int tid = threadIdx.x;
    const int wv = tid >> 6;
    const int lane = tid & 63;
    const int l15 = lane & 15;
    const int l4 = lane >> 4;
    const int row0 = blockIdx.x * 64 + wv * 16;

    for (int q = tid; q < 2048; q += 256) {
        int r = q >> 4, u = q & 15;
        *(uint4*)&Bs[r * 128 + (u ^ (r & 7)) * 8] = *(const uint4*)(Bt + r * D + u * 8);
    }

    bf16x8 afrag[4];
    {
        int r = row0 + l15;
        int rc = (r < NN) ? r : (NN - 1);
#pragma unroll
        for (int kk = 0; kk < 4; ++kk)
            afrag[kk] = *(const bf16x8*)(A + rc * D + kk * 32 + l4 * 8);
    }
    __syncthreads();

    const int rsw = l15 & 7;
    f32x4 acc[8];
#pragma unroll
    for (int n = 0; n < 8; ++n) acc[n] = (f32x4){0.f, 0.f, 0.f, 0.f};
#pragma unroll
    for (int n = 0; n < 8; ++n) {
#pragma unroll
        for (int kk = 0; kk < 4; ++kk) {
            bf16x8 bfrag = *(const bf16x8*)&Bs[(n * 16 + l15) * 128 + ((kk * 4 + l4) ^ rsw) * 8];
            acc[n] = __builtin_amdgcn_mfma_f32_16x16x32_bf16(afrag[kk], bfrag, acc[n], 0, 0, 0);
        }
    }
#pragma unroll
    for (int n = 0; n < 8; ++n) {
        int col = n * 16 + l15;
        float bv = bias[col];
#pragma unroll
        for (int r = 0; r < 4; ++r) {
            int row = row0 + l4 * 4 + r;
            if (row < NN) out[(size_t)row * D + col] = (bf16_t)(acc[n][r] + bv);
        }
    }
}

// D-split gather propagate: blockIdx%8 selects XCD; XCDs 0-3 handle features
// 0-63, XCDs 4-7 features 64-127 -> per-XCD L2 working set halves (6.4 MB).
// 32-lane group per (node, half): 128 B coalesced row reads, unroll x4.
// POST 0: out bf16 = relu(v + bias);  POST 1: out bf16 = v
template <int POST>
__global__ __launch_bounds__(256) void prop_half(
    const int* __restrict__ colp, const int* __restrict__ ends,
    const unsigned int* __restrict__ srcs, const float* __restrict__ dis,
    const bf16_t* __restrict__ hin, bf16_t* __restrict__ hout,
    const float* __restrict__ bias) {
    const int b = blockIdx.x;
    const int half = (b & 7) >> 2;            // XCD group selects feature half
    const int ord = (b >> 3) * 4 + (b & 3);   // ordinal within half
    const int sub = threadIdx.x >> 5;
    const int l32 = threadIdx.x & 31;
    const int n = ord * 8 + sub;
    if (n >= NN) return;
    const int start = colp[n];
    const int end = ends[n];
    const float dn = dis[n];
    const unsigned int* hinh = (const unsigned int*)(hin + half * 64);  // +128 B
    unsigned int u = hinh[(size_t)n * 64 + l32];
    float ax = dn * bf_lo(u), ay = dn * bf_hi(u);
    int i = start;
    for (; i + 3 < end; i += 4) {
        unsigned int e0 = srcs[i], e1 = srcs[i + 1], e2 = srcs[i + 2], e3 = srcs[i + 3];
        unsigned int u0 = hinh[(size_t)(e0 & 0xFFFFu) * 64 + l32];
        unsigned int u1 = hinh[(size_t)(e1 & 0xFFFFu) * 64 + l32];
        unsigned int u2 = hinh[(size_t)(e2 & 0xFFFFu) * 64 + l32];
        unsigned int u3 = hinh[(size_t)(e3 & 0xFFFFu) * 64 + l32];
        float w0 = bf_hi(e0), w1 = bf_hi(e1), w2 = bf_hi(e2), w3 = bf_hi(e3);
        ax = fmaf(w0, bf_lo(u0), ax); ay = fmaf(w0, bf_hi(u0), ay);
        ax = fmaf(w1, bf_lo(u1), ax); ay = fmaf(w1, bf_hi(u1), ay);
        ax = fmaf(w2, bf_lo(u2), ax); ay = fmaf(w2, bf_hi(u2), ay);
        ax = fmaf(w3, bf_lo(u3), ax); ay = fmaf(w3, bf_hi(u3), ay);
    }
    for (; i < end; ++i) {
        unsigned int e0 = srcs[i];
        unsigned int u0 = hinh[(size_t)(e0 & 0xFFFFu) * 64 + l32];
        float w0 = bf_hi(e0);
        ax = fmaf(w0, bf_lo(u0), ax); ay = fmaf(w0, bf_hi(u0), ay);
    }
    float vx = dn * ax, vy = dn * ay;
    if (POST == 0) {
        float2 bb = ((const float2*)bias)[half * 32 + l32];
        vx = fmaxf(vx + bb.x, 0.f);
        vy = fmaxf(vy + bb.y, 0.f);
    }
    unsigned int pk = (unsigned int)f2bf_bits(vx) | ((unsigned int)f2bf_bits(vy) << 16);
    ((unsigned int*)(hout + (size_t)n * D + half * 64))[l32] = pk;
}

// node head on bf16 node_rep; writes packed tb = (t1, t2, batch, 0) per node
__global__ __launch_bounds__(256) void node_kernel(
    const bf16_t* __restrict__ h, const float* __restrict__ bh1,
    const float* __restrict__ We, const float* __restrict__ Wn,
    const float* __restrict__ bnb, const int* __restrict__ batch,
    float* __restrict__ nkey_out, float4* __restrict__ tb,
    float* __restrict__ accN) {
    __shared__ float binK[NG], binE[NG], binZ[NG], binC[NG];
    const int tid = threadIdx.x;
    for (int i = tid; i < NG; i += 256) { binK[i] = 0.f; binE[i] = 0.f; binZ[i] = 0.f; binC[i] = 0.f; }
    __syncthreads();

    const int CHUNK = 98;
    int start = blockIdx.x * CHUNK;
    int end = min(start + CHUNK, NN);
    int sub = tid >> 5;
    int l32 = tid & 31;
    float bnb0 = bnb[0];

    float4 w1 = ((const float4*)We)[l32];
    float4 w2 = ((const float4*)(We + D))[l32];
    float4 wn = ((const float4*)Wn)[l32];
    float4 bb = ((const float4*)bh1)[l32];

    for (int n = start + sub; n < end; n += 8) {
        uint2 pk = ((const uint2*)(h + (size_t)n * D))[l32];
        float v0 = bf_lo(pk.x) + bb.x;
        float v1 = bf_hi(pk.x) + bb.y;
        float v2 = bf_lo(pk.y) + bb.z;
        float v3 = bf_hi(pk.y) + bb.w;
        float s1 = v0 * w1.x + v1 * w1.y + v2 * w1.z + v3 * w1.w;
        float s2 = v0 * w2.x + v1 * w2.y + v2 * w2.z + v3 * w2.w;
        float s3 = v0 * wn.x + v1 * wn.y + v2 * wn.z + v3 * wn.w;
        for (int o = 16; o; o >>= 1) {
            s1 += __shfl_xor(s1, o);
            s2 += __shfl_xor(s2, o);
            s3 += __shfl_xor(s3, o);
        }
        if (l32 == 0) {
            float nk = sigmoidf(s3 + bnb0);
            nkey_out[n] = nk;
            int g = batch[n];
            tb[n] = make_float4(s1, s2, __int_as_float(g), 0.f);
            atomicAdd(&binK[g], nk);
            atomicAdd(&binE[g], 1.0f - nk);
            if (nk > 0.f) atomicAdd(&binZ[g], 1.0f);
            atomicAdd(&binC[g], 1.0f);
        }
    }
    __syncthreads();
    if (start < NN) {
        int glo = batch[start];
        int ghi = batch[end - 1];
        for (int g = glo + tid; g <= ghi; g += 256) {
            unsafeAtomicAdd(&accN[g], binK[g]);
            unsafeAtomicAdd(&accN[NG + g], binE[g]);
            unsafeAtomicAdd(&accN[2 * NG + g], binZ[g]);
            unsafeAtomicAdd(&accN[3 * NG + g], binC[g]);
        }
    }
}

// edge head + inlined final reduction; tb packs (t1,t2,batch) -> 2 x 16B gathers/edge
__global__ __launch_bounds__(256) void edge_final(
    const int* __restrict__ ei, const float4* __restrict__ tb,
    const float* __restrict__ be, float* __restrict__ ekey_out,
    float* __restrict__ accE, const float* __restrict__ accN,
    int* __restrict__ ctr, float* __restrict__ out) {
    __shared__ float binK[NG], binE[NG], binZ[NG], binC[NG];
    __shared__ int isLast;
    const int tid = threadIdx.x;
    for (int i = tid; i < NG; i += 256) { binK[i] = 0.f; binE[i] = 0.f; binZ[i] = 0.f; binC[i] = 0.f; }
    __syncthreads();
    float be0 = be[0];
    int stride4 = gridDim.x * 256;
    for (int q = blockIdx.x * 256 + tid; q < NE / 4; q += stride4) {
        int4 r4 = ((const int4*)ei)[q];
        int4 c4 = ((const int4*)(ei + NE))[q];
        float4 tr0 = tb[r4.x], tr1 = tb[r4.y], tr2 = tb[r4.z], tr3 = tb[r4.w];
        float4 tc0 = tb[c4.x], tc1 = tb[c4.y], tc2 = tb[c4.z], tc3 = tb[c4.w];
        int g0 = __float_as_int(tr0.z), g1 = __float_as_int(tr1.z);
        int g2 = __float_as_int(tr2.z), g3 = __float_as_int(tr3.z);
        float e0 = sigmoidf(tr0.x + tc0.y + be0);
        float e1 = sigmoidf(tr1.x + tc1.y + be0);
        float e2 = sigmoidf(tr2.x + tc2.y + be0);
        float e3 = sigmoidf(tr3.x + tc3.y + be0);
        ((float4*)ekey_out)[q] = make_float4(e0, e1, e2, e3);
        atomicAdd(&binK[g0], e0); atomicAdd(&binE[g0], 1.0f - e0);
        if (e0 > 0.f) atomicAdd(&binZ[g0], 1.0f);
        atomicAdd(&binC[g0], 1.0f);
        atomicAdd(&binK[g1], e1); atomicAdd(&binE[g1], 1.0f - e1);
        if (e1 > 0.f) atomicAdd(&binZ[g1], 1.0f);
        atomicAdd(&binC[g1], 1.0f);
        atomicAdd(&binK[g2], e2); atomicAdd(&binE[g2], 1.0f - e2);
        if (e2 > 0.f) atomicAdd(&binZ[g2], 1.0f);
        atomicAdd(&binC[g2], 1.0f);
        atomicAdd(&binK[g3], e3); atomicAdd(&binE[g3], 1.0f - e3);
        if (e3 > 0.f) atomicAdd(&binZ[g3], 1.0f);
        atomicAdd(&binC[g3], 1.0f);
    }
    __syncthreads();
    for (int g = tid; g < NG; g += 256) {
        if (binC[g] != 0.f) {
            unsafeAtomicAdd(&accE[g], binK[g]);
            unsafeAtomicAdd(&accE[NG + g], binE[g]);
            unsafeAtomicAdd(&accE[2 * NG + g], binZ[g]);
            unsafeAtomicAdd(&accE[3 * NG + g], binC[g]);
        }
    }
    __syncthreads();
    if (tid == 0) {
        __threadfence();
        int old = atomicAdd(ctr, 1);
        isLast = (old == (int)gridDim.x - 1);
    }
    __syncthreads();
    if (isLast) {
        __threadfence();
        for (int g = tid; g < NG; g += 256) {
            out[O_NKN + g] = accN[g] + 1e-8f;
            out[O_NEN + g] = accN[NG + g] + 1e-8f;
            out[O_EKN + g] = accE[g] + 1e-8f;
            out[O_EEN + g] = accE[NG + g] + 1e-8f;
            out[O_NZN + g] = accN[2 * NG + g] / accN[3 * NG + g];
            out[O_NZE + g] = accE[2 * NG + g] / accE[3 * NG + g];
        }
    }
}

extern "C" void kernel_launch(void* const* d_in, const int* in_sizes, int n_in,
                              void* d_out, int out_size, void* d_ws, size_t ws_size,
                              hipStream_t stream) {
    const float* x     = (const float*)d_in[0];
    const int*   ei    = (const int*)d_in[1];
    const int*   batch = (const int*)d_in[2];
    const float* W     = (const float*)d_in[4];
    const float* bh    = (const float*)d_in[5];   // [2][128]
    const float* gamma = (const float*)d_in[6];
    const float* beta  = (const float*)d_in[7];
    const float* mean  = (const float*)d_in[8];
    const float* var   = (const float*)d_in[9];
    const float* We    = (const float*)d_in[10];
    const float* be    = (const float*)d_in[11];
    const float* Wn    = (const float*)d_in[12];
    const float* bnb   = (const float*)d_in[13];

    float* ws  = (float*)d_ws;
    float* out = (float*)d_out;

    float*        accN = ws + OFF_ACCN;
    float*        accE = ws + OFF_ACCE;
    int*          ctr  = (int*)(ws + OFF_CTR);
    int*          ctr2 = (int*)(ws + OFF_CTR2);
    float*        dis  = ws + OFF_DIS;
    int*          cnt  = (int*)(ws + OFF_CNT);
    int*          colp = (int*)(ws + OFF_COLP);
    int*          ends = (int*)(ws + OFF_ENDS);
    int*          bsum = (int*)(ws + OFF_BSUM);
    float*        bp   = ws + OFF_BP;
    bf16_t*       Wpt  = (bf16_t*)(ws + OFF_WPT);
    int*          PR   = (int*)(ws + OFF_PR);
    int*          PC   = (int*)(ws + OFF_PC);
    unsigned int* srcs = (unsigned int*)(ws + OFF_SRCS);  // aliases PR
    float4*       tb   = (float4*)(ws + OFF_TB);          // after srcs, PR region
    bf16_t*       hbfA = (bf16_t*)(ws + OFF_HBFA);
    bf16_t*       hbfB = (bf16_t*)(ws + OFF_HBFB);

    hipMemsetAsync(d_ws, 0, (size_t)ZERO_FLOATS * sizeof(float), stream);

    // CSR count + prep_w (merged)
    count_prep<<<dim3(2, NCHUNK, 3), 256, RSZC * sizeof(int), stream>>>(
        ei, PR, PC, W, gamma, beta, mean, var, Wpt, bp);
    const int NB = (NN + 255) / 256;  // 196
    csr_mid_scan<<<NB, 256, 0, stream>>>(PR, PC, dis, cnt, colp, bsum, ends, ctr2);
    fill_part<<<dim3(4, NCHUNK), 256, 0, stream>>>(ei, colp, PC, dis, srcs);

    const int GB = (NN + 63) / 64;  // 782
    // layers 0+1 fused: hbfB = bf16( relu(x@Wp0+bp0) @ Wp1 + bp1 )
    gemm01<<<GB, 256, 81920, stream>>>(x, Wpt, Wpt + D * D, bp, bp + D, hbfB);
    // propagate 1 + fused relu(v + bh0): hbfA = bf16(relu(P(hbfB) + bh0))
    prop_half<0><<<12504, 256, 0, stream>>>(colp, ends, srcs, dis, hbfB, hbfA, bh);
    // layer 2 linear: hbfB = bf16(hbfA @ Wp2 + bp2)
    gemm2<<<GB, 256, 0, stream>>>(hbfA, Wpt + 2 * D * D, bp + 2 * D, hbfB);
    // propagate 2: hbfA = bf16(P(hbfB))  (node_rep)
    prop_half<1><<<12504, 256, 0, stream>>>(colp, ends, srcs, dis, hbfB, hbfA, nullptr);

    node_kernel<<<512, 256, 0, stream>>>(hbfA, bh + D, We, Wn, bnb, batch,
                                         out + O_NKEY, tb, accN);
    edge_final<<<EDGE_BLOCKS, 256, 0, stream>>>(ei, tb, be, out + O_EKEY,
                                                accE, accN, ctr, out);
}

// Round 13
// 204.937 us; speedup vs baseline: 1.2301x; 1.2301x over previous
//
#include <hip/hip_runtime.h>
#include <cstddef>
#include <cstring>

#define NN 50000
#define NNP 50048
#define NE 800000
#define D 128
#define NG 512
#define BN_EPS 1e-5f
#define RSZC 25000    // count: nodes per range (2 ranges, 100 KB dyn LDS)
#define RSZF 12500    // fill: nodes per range (4 ranges, 50 KB LDS)
#define NCHUNK 64
#define CSZ 12500     // edges per chunk
#define EDGE_BLOCKS 256

typedef __bf16 bf16_t;
typedef __bf16 bf16x8 __attribute__((ext_vector_type(8)));
typedef float f32x4 __attribute__((ext_vector_type(4)));

// ---- workspace layout (float offsets) ----
#define OFF_ACCN 0            // float[4*512]
#define OFF_ACCE 2048         // float[4*512]
#define OFF_CTR  4096         // int[1]
#define ZERO_FLOATS 4160      // zeroed region = [0, here)
#define OFF_DIS  4160         // float[50048]
#define OFF_CNT  54208        // int[50048]
#define OFF_COLP 104256      // int[50048]
#define OFF_ENDS 154304      // int[50048]
#define OFF_BSUM 204352      // int[256]
#define OFF_BP   304896      // float[3*128 padded]
#define OFF_WPT  305408      // bf16[3*128*128] (24576 floats)
#define OFF_PR   329984      // int[64][50048] = 3203072
#define OFF_PC   3533056     // int[64][50048] = 3203072 (CPS after csr_mid)
#define OFF_SRCS OFF_PR      // uint[800000], aliases PR (dead after csr_mid)
#define OFF_TB   1129984     // float4[50048] = 200192 floats, after srcs in PR region
#define OFF_HBFA 7536128     // bf16[50048*128] (3203072 floats)
#define OFF_HBFB 10739200    // bf16[50048*128]

// ---- output layout (float offsets in d_out) ----
#define O_NKEY 0
#define O_EKEY 50000
#define O_NKN  850000
#define O_NEN  850512
#define O_EKN  851024
#define O_EEN  851536
#define O_NZN  852048
#define O_NZE  852560

__device__ __forceinline__ float sigmoidf(float x) {
    return 1.0f / (1.0f + expf(-x));
}

__device__ __forceinline__ unsigned short f2bf_bits(float f) {
    bf16_t h = (bf16_t)f;
    unsigned short u;
    __builtin_memcpy(&u, &h, 2);
    return u;
}

__device__ __forceinline__ float bf_lo(unsigned int u) {
    return __uint_as_float(u << 16);
}
__device__ __forceinline__ float bf_hi(unsigned int u) {
    return __uint_as_float(u & 0xFFFF0000u);
}

// count histograms (2 node ranges x 64 chunks x 2 dirs) + prep_w rides on z==2.
__global__ __launch_bounds__(256) void count_prep(const int* __restrict__ ei,
                                                  int* __restrict__ PR,
                                                  int* __restrict__ PC,
                                                  const float* __restrict__ W,
                                                  const float* __restrict__ gamma,
                                                  const float* __restrict__ beta,
                                                  const float* __restrict__ mean,
                                                  const float* __restrict__ var,
                                                  bf16_t* __restrict__ Wpt,
                                                  float* __restrict__ bp) {
    const int tid = threadIdx.x;
    if (blockIdx.z == 2) {
        if (blockIdx.x == 0 && blockIdx.y < 3 && tid < D) {
            int l = blockIdx.y;
            int j = tid;
            float acc = 0.f;
            for (int k = 0; k < D; ++k) {
                float a = gamma[l * D + k] * rsqrtf(var[l * D + k] + BN_EPS);
                float c = beta[l * D + k] - mean[l * D + k] * a;
                float w = W[l * D * D + k * D + j];
                Wpt[l * D * D + j * D + k] = (bf16_t)(a * w);
                acc = fmaf(c, w, acc);
            }
            bp[l * D + j] = acc;
        }
        return;
    }
    extern __shared__ int hist[];
    const int r = blockIdx.x, p = blockIdx.y, dirz = blockIdx.z;
    for (int i = tid; i < RSZC; i += 256) hist[i] = 0;
    __syncthreads();
    const int base = r * RSZC;
    const int4* ids = (const int4*)(ei + dirz * NE + p * CSZ);
    for (int i = tid; i < CSZ / 4; i += 256) {
        int4 v = ids[i];
        int d0 = v.x - base, d1 = v.y - base, d2 = v.z - base, d3 = v.w - base;
        if ((unsigned)d0 < RSZC) atomicAdd(&hist[d0], 1);
        if ((unsigned)d1 < RSZC) atomicAdd(&hist[d1], 1);
        if ((unsigned)d2 < RSZC) atomicAdd(&hist[d2], 1);
        if ((unsigned)d3 < RSZC) atomicAdd(&hist[d3], 1);
    }
    __syncthreads();
    int* dst = (dirz == 0 ? PR : PC) + p * NNP + base;
    for (int i = tid; i < RSZC; i += 256) dst[i] = hist[i];
}

// fused: rowsum->dis, colscan->cnt + per-chunk offsets in PC, block-local scan
__global__ void csr_mid(const int* __restrict__ PR, int* __restrict__ PC,
                        float* __restrict__ dis, int* __restrict__ cnt,
                        int* __restrict__ colp, int* __restrict__ bsum) {
    __shared__ int s[256];
    int t = threadIdx.x;
    int i = blockIdx.x * 256 + t;
    int run = 0;
    if (i < NN) {
        int dg = 0;
#pragma unroll 8
        for (int k = 0; k < NCHUNK; ++k) dg += PR[k * NNP + i];
        dis[i] = rsqrtf((float)(dg + 1));
        for (int k = 0; k < NCHUNK; ++k) {
            int v = PC[k * NNP + i];
            PC[k * NNP + i] = run;
            run += v;
        }
        cnt[i] = run;
    }
    s[t] = run;
    __syncthreads();
    for (int o = 1; o < 256; o <<= 1) {
        int add = (t >= o) ? s[t - o] : 0;
        __syncthreads();
        s[t] += add;
        __syncthreads();
    }
    if (i < NN) colp[i] = s[t] - run;  // local exclusive
    if (t == 255) bsum[blockIdx.x] = s[255];
}

// scan3 with inlined block-offset reduction
__global__ void scan3(int* __restrict__ colp, const int* __restrict__ bsum,
                      const int* __restrict__ cnt, int* __restrict__ ends) {
    __shared__ int s[256];
    int t = threadIdx.x;
    int bid = blockIdx.x;
    s[t] = (t < bid) ? bsum[t] : 0;   // NB=196 <= 256
    __syncthreads();
    for (int o = 128; o; o >>= 1) {
        if (t < o) s[t] += s[t + o];
        __syncthreads();
    }
    int boff = s[0];
    int i = bid * 256 + t;
    if (i < NN) {
        int v = colp[i] + boff;
        colp[i] = v;
        ends[i] = v + cnt[i];
    }
}

// MERGED heterogeneous dispatch: blocks 0..255 = CSR fill (independent of GEMM);
// blocks 256..1037 = fused layers 0+1 GEMM. No data dependency between halves.
__global__ __launch_bounds__(256) void fill_gemm01(
    const int* __restrict__ ei, const int* __restrict__ colp,
    const int* __restrict__ CPS, const float* __restrict__ dis,
    unsigned int* __restrict__ srcs,
    const float* __restrict__ X, const bf16_t* __restrict__ Bt0,
    const bf16_t* __restrict__ Bt1, const float* __restrict__ bias0,
    const float* __restrict__ bias1, bf16_t* __restrict__ out) {
    extern __shared__ __align__(16) unsigned short smem[];
    const int bid = blockIdx.x;
    const int tid = threadIdx.x;

    if (bid < 256) {
        // ---- CSR fill: packed entries src|bf16(dis[src])<<16 ----
        int* curs = (int*)smem;   // RSZF ints = 50 KB
        const int r = bid & 3, p = bid >> 2;
        const int base = r * RSZF;
        for (int i = tid; i < RSZF; i += 256)
            curs[i] = colp[base + i] + CPS[p * NNP + base + i];
        __syncthreads();
        const int4* rows = (const int4*)(ei + p * CSZ);
        const int4* cols = (const int4*)(ei + NE + p * CSZ);
        for (int i = tid; i < CSZ / 4; i += 256) {
            int4 rv = rows[i];
            int4 cv = cols[i];
            int d;
            d = cv.x - base;
            if ((unsigned)d < RSZF)
                srcs[atomicAdd(&curs[d], 1)] =
                    (unsigned int)rv.x | ((unsigned int)f2bf_bits(dis[rv.x]) << 16);
            d = cv.y - base;
            if ((unsigned)d < RSZF)
                srcs[atomicAdd(&curs[d], 1)] =
                    (unsigned int)rv.y | ((unsigned int)f2bf_bits(dis[rv.y]) << 16);
            d = cv.z - base;
            if ((unsigned)d < RSZF)
                srcs[atomicAdd(&curs[d], 1)] =
                    (unsigned int)rv.z | ((unsigned int)f2bf_bits(dis[rv.z]) << 16);
            d = cv.w - base;
            if ((unsigned)d < RSZF)
                srcs[atomicAdd(&curs[d], 1)] =
                    (unsigned int)rv.w | ((unsigned int)f2bf_bits(dis[rv.w]) << 16);
        }
        return;
    }

    // ---- fused GEMM layers 0+1, B0/B1/h0 in LDS (XOR-swizzled 16B units) ----
    unsigned short* Bs0 = smem;             // 32 KB
    unsigned short* Bs1 = smem + 16384;     // 32 KB
    unsigned short* As  = smem + 32768;     // 16 KB
    const int wv = tid >> 6;
    const int lane = tid & 63;
    const int l15 = lane & 15;
    const int l4 = lane >> 4;
    const int row0 = (bid - 256) * 64;

    for (int q = tid; q < 2048; q += 256) {
        int r = q >> 4, u = q & 15;
        int us = (u ^ (r & 7)) * 8;
        *(uint4*)&Bs0[r * 128 + us] = *(const uint4*)(Bt0 + r * D + u * 8);
        *(uint4*)&Bs1[r * 128 + us] = *(const uint4*)(Bt1 + r * D + u * 8);
    }

    bf16x8 afrag[4];
    {
        int r = row0 + wv * 16 + l15;
        int rc = (r < NN) ? r : (NN - 1);
#pragma unroll
        for (int kk = 0; kk < 4; ++kk) {
            int off = rc * D + kk * 32 + l4 * 8;
            float4 f0 = *(const float4*)(X + off);
            float4 f1 = *(const float4*)(X + off + 4);
            bf16x8 a;
            a[0] = (bf16_t)f0.x; a[1] = (bf16_t)f0.y;
            a[2] = (bf16_t)f0.z; a[3] = (bf16_t)f0.w;
            a[4] = (bf16_t)f1.x; a[5] = (bf16_t)f1.y;
            a[6] = (bf16_t)f1.z; a[7] = (bf16_t)f1.w;
            afrag[kk] = a;
        }
    }
    __syncthreads();

    const int rsw = l15 & 7;
    f32x4 acc[8];
#pragma unroll
    for (int n = 0; n < 8; ++n) acc[n] = (f32x4){0.f, 0.f, 0.f, 0.f};
#pragma unroll
    for (int n = 0; n < 8; ++n) {
#pragma unroll
        for (int kk = 0; kk < 4; ++kk) {
            bf16x8 bfrag = *(const bf16x8*)&Bs0[(n * 16 + l15) * 128 + ((kk * 4 + l4) ^ rsw) * 8];
            acc[n] = __builtin_amdgcn_mfma_f32_16x16x32_bf16(afrag[kk], bfrag, acc[n], 0, 0, 0);
        }
    }
#pragma unroll
    for (int n = 0; n < 8; ++n) {
        int col = n * 16 + l15;
        float bv = bias0[col];
#pragma unroll
        for (int r = 0; r < 4; ++r) {
            int rl = wv * 16 + l4 * 4 + r;
            float v = fmaxf(acc[n][r] + bv, 0.f);
            int cs = ((col >> 3) ^ (rl & 7));
            As[rl * 128 + cs * 8 + (col & 7)] = f2bf_bits(v);
        }
    }
    __syncthreads();

    const int rl = wv * 16 + l15;
    bf16x8 af2[4];
#pragma unroll
    for (int kk = 0; kk < 4; ++kk) {
        int cs = (kk * 4 + l4) ^ (rl & 7);
        af2[kk] = *(const bf16x8*)&As[rl * 128 + cs * 8];
    }
#pragma unroll
    for (int n = 0; n < 8; ++n) acc[n] = (f32x4){0.f, 0.f, 0.f, 0.f};
#pragma unroll
    for (int n = 0; n < 8; ++n) {
#pragma unroll
        for (int kk = 0; kk < 4; ++kk) {
            bf16x8 bfrag = *(const bf16x8*)&Bs1[(n * 16 + l15) * 128 + ((kk * 4 + l4) ^ rsw) * 8];
            acc[n] = __builtin_amdgcn_mfma_f32_16x16x32_bf16(af2[kk], bfrag, acc[n], 0, 0, 0);
        }
    }
#pragma unroll
    for (int n = 0; n < 8; ++n) {
        int col = n * 16 + l15;
        float bv = bias1[col];
#pragma unroll
        for (int r = 0; r < 4; ++r) {
            int row = row0 + wv * 16 + l4 * 4 + r;
            if (row < NN) out[(size_t)row * D + col] = (bf16_t)(acc[n][r] + bv);
        }
    }
}

// layer-2 GEMM with B staged in LDS
__global__ __launch_bounds__(256) void gemm2(const bf16_t* __restrict__ A,
                                             const bf16_t* __restrict__ Bt,
                                             const float* __restrict__ bias,
                                             bf16_t* __restrict__ out) {
    __shared__ __align__(16) unsigned short Bs[128 * 128];
    const int tid = threadIdx.x;
    const int wv = tid >> 6;
    const int lane = tid & 63;
    const int l15 = lane & 15;
    const int l4 = lane >> 4;
    const int row0 = blockIdx.x * 64 + wv * 16;

    for (int q = tid; q < 2048; q += 256) {
        int r = q >> 4, u = q & 15;
        *(uint4*)&Bs[r * 128 + (u ^ (r & 7)) * 8] = *(const uint4*)(Bt + r * D + u * 8);
    }

    bf16x8 afrag[4];
    {
        int r = row0 + l15;
        int rc = (r < NN) ? r : (NN - 1);
#pragma unroll
        for (int kk = 0; kk < 4; ++kk)
            afrag[kk] = *(const bf16x8*)(A + rc * D + kk * 32 + l4 * 8);
    }
    __syncthreads();

    const int rsw = l15 & 7;
    f32x4 acc[8];
#pragma unroll
    for (int n = 0; n < 8; ++n) acc[n] = (f32x4){0.f, 0.f, 0.f, 0.f};
#pragma unroll
    for (int n = 0; n < 8; ++n) {
#pragma unroll
        for (int kk = 0; kk < 4; ++kk) {
            bf16x8 bfrag = *(const bf16x8*)&Bs[(n * 16 + l15) * 128 + ((kk * 4 + l4) ^ rsw) * 8];
            acc[n] = __builtin_amdgcn_mfma_f32_16x16x32_bf16(afrag[kk], bfrag, acc[n], 0, 0, 0);
        }
    }
#pragma unroll
    for (int n = 0; n < 8; ++n) {
        int col = n * 16 + l15;
        float bv = bias[col];
#pragma unroll
        for (int r = 0; r < 4; ++r) {
            int row = row0 + l4 * 4 + r;
            if (row < NN) out[(size_t)row * D + col] = (bf16_t)(acc[n][r] + bv);
        }
    }
}

// gather propagate (R11 proven): one wave per node, unroll x4, packed srcs.
// POST 0: out bf16 = relu(v + bias);  POST 1: out bf16 = v
template <int POST>
__global__ __launch_bounds__(256) void prop_gather(
    const int* __restrict__ colp, const int* __restrict__ ends,
    const unsigned int* __restrict__ srcs, const float* __restrict__ dis,
    const bf16_t* __restrict__ hin, bf16_t* __restrict__ hout,
    const float* __restrict__ bias) {
    int n = blockIdx.x * 4 + (threadIdx.x >> 6);
    n = __builtin_amdgcn_readfirstlane(n);   // wave-uniform: scalarize CSR chain
    int lane = threadIdx.x & 63;
    if (n >= NN) return;
    const int start = colp[n];
    const int end = ends[n];
    const float dn = dis[n];
    unsigned int u = ((const unsigned int*)(hin + (size_t)n * D))[lane];
    float ax = dn * bf_lo(u), ay = dn * bf_hi(u);
    int i = start;
    for (; i + 3 < end; i += 4) {
        unsigned int e0 = srcs[i], e1 = srcs[i + 1], e2 = srcs[i + 2], e3 = srcs[i + 3];
        unsigned int u0 = ((const unsigned int*)(hin + (size_t)(e0 & 0xFFFFu) * D))[lane];
        unsigned int u1 = ((const unsigned int*)(hin + (size_t)(e1 & 0xFFFFu) * D))[lane];
        unsigned int u2 = ((const unsigned int*)(hin + (size_t)(e2 & 0xFFFFu) * D))[lane];
        unsigned int u3 = ((const unsigned int*)(hin + (size_t)(e3 & 0xFFFFu) * D))[lane];
        float w0 = bf_hi(e0), w1 = bf_hi(e1), w2 = bf_hi(e2), w3 = bf_hi(e3);
        ax = fmaf(w0, bf_lo(u0), ax); ay = fmaf(w0, bf_hi(u0), ay);
        ax = fmaf(w1, bf_lo(u1), ax); ay = fmaf(w1, bf_hi(u1), ay);
        ax = fmaf(w2, bf_lo(u2), ax); ay = fmaf(w2, bf_hi(u2), ay);
        ax = fmaf(w3, bf_lo(u3), ax); ay = fmaf(w3, bf_hi(u3), ay);
    }
    for (; i < end; ++i) {
        unsigned int e0 = srcs[i];
        unsigned int u0 = ((const unsigned int*)(hin + (size_t)(e0 & 0xFFFFu) * D))[lane];
        float w0 = bf_hi(e0);
        ax = fmaf(w0, bf_lo(u0), ax); ay = fmaf(w0, bf_hi(u0), ay);
    }
    float vx = dn * ax, vy = dn * ay;
    if (POST == 0) {
        float2 bb = ((const float2*)bias)[lane];
        vx = fmaxf(vx + bb.x, 0.f);
        vy = fmaxf(vy + bb.y, 0.f);
    }
    unsigned int pk = (unsigned int)f2bf_bits(vx) | ((unsigned int)f2bf_bits(vy) << 16);
    ((unsigned int*)(hout + (size_t)n * D))[lane] = pk;
}

// node head on bf16 node_rep; writes packed tb = (t1, t2, batch, 0) per node
__global__ __launch_bounds__(256) void node_kernel(
    const bf16_t* __restrict__ h, const float* __restrict__ bh1,
    const float* __restrict__ We, const float* __restrict__ Wn,
    const float* __restrict__ bnb, const int* __restrict__ batch,
    float* __restrict__ nkey_out, float4* __restrict__ tb,
    float* __restrict__ accN) {
    __shared__ float binK[NG], binE[NG], binZ[NG], binC[NG];
    const int tid = threadIdx.x;
    for (int i = tid; i < NG; i += 256) { binK[i] = 0.f; binE[i] = 0.f; binZ[i] = 0.f; binC[i] = 0.f; }
    __syncthreads();

    const int CHUNK = 98;
    int start = blockIdx.x * CHUNK;
    int end = min(start + CHUNK, NN);
    int sub = tid >> 5;
    int l32 = tid & 31;
    float bnb0 = bnb[0];

    float4 w1 = ((const float4*)We)[l32];
    float4 w2 = ((const float4*)(We + D))[l32];
    float4 wn = ((const float4*)Wn)[l32];
    float4 bb = ((const float4*)bh1)[l32];

    for (int n = start + sub; n < end; n += 8) {
        uint2 pk = ((const uint2*)(h + (size_t)n * D))[l32];
        float v0 = bf_lo(pk.x) + bb.x;
        float v1 = bf_hi(pk.x) + bb.y;
        float v2 = bf_lo(pk.y) + bb.z;
        float v3 = bf_hi(pk.y) + bb.w;
        float s1 = v0 * w1.x + v1 * w1.y + v2 * w1.z + v3 * w1.w;
        float s2 = v0 * w2.x + v1 * w2.y + v2 * w2.z + v3 * w2.w;
        float s3 = v0 * wn.x + v1 * wn.y + v2 * wn.z + v3 * wn.w;
        for (int o = 16; o; o >>= 1) {
            s1 += __shfl_xor(s1, o);
            s2 += __shfl_xor(s2, o);
            s3 += __shfl_xor(s3, o);
        }
        if (l32 == 0) {
            float nk = sigmoidf(s3 + bnb0);
            nkey_out[n] = nk;
            int g = batch[n];
            tb[n] = make_float4(s1, s2, __int_as_float(g), 0.f);
            atomicAdd(&binK[g], nk);
            atomicAdd(&binE[g], 1.0f - nk);
            if (nk > 0.f) atomicAdd(&binZ[g], 1.0f);
            atomicAdd(&binC[g], 1.0f);
        }
    }
    __syncthreads();
    if (start < NN) {
        int glo = batch[start];
        int ghi = batch[end - 1];
        for (int g = glo + tid; g <= ghi; g += 256) {
            unsafeAtomicAdd(&accN[g], binK[g]);
            unsafeAtomicAdd(&accN[NG + g], binE[g]);
            unsafeAtomicAdd(&accN[2 * NG + g], binZ[g]);
            unsafeAtomicAdd(&accN[3 * NG + g], binC[g]);
        }
    }
}

// edge head + inlined final reduction; tb packs (t1,t2,batch) -> 2 x 16B gathers/edge
__global__ __launch_bounds__(256) void edge_final(
    const int* __restrict__ ei, const float4* __restrict__ tb,
    const float* __restrict__ be, float* __restrict__ ekey_out,
    float* __restrict__ accE, const float* __restrict__ accN,
    int* __restrict__ ctr, float* __restrict__ out) {
    __shared__ float binK[NG], binE[NG], binZ[NG], binC[NG];
    __shared__ int isLast;
    const int tid = threadIdx.x;
    for (int i = tid; i < NG; i += 256) { binK[i] = 0.f; binE[i] = 0.f; binZ[i] = 0.f; binC[i] = 0.f; }
    __syncthreads();
    float be0 = be[0];
    int stride4 = gridDim.x * 256;
    for (int q = blockIdx.x * 256 + tid; q < NE / 4; q += stride4) {
        int4 r4 = ((const int4*)ei)[q];
        int4 c4 = ((const int4*)(ei + NE))[q];
        float4 tr0 = tb[r4.x], tr1 = tb[r4.y], tr2 = tb[r4.z], tr3 = tb[r4.w];
        float4 tc0 = tb[c4.x], tc1 = tb[c4.y], tc2 = tb[c4.z], tc3 = tb[c4.w];
        int g0 = __float_as_int(tr0.z), g1 = __float_as_int(tr1.z);
        int g2 = __float_as_int(tr2.z), g3 = __float_as_int(tr3.z);
        float e0 = sigmoidf(tr0.x + tc0.y + be0);
        float e1 = sigmoidf(tr1.x + tc1.y + be0);
        float e2 = sigmoidf(tr2.x + tc2.y + be0);
        float e3 = sigmoidf(tr3.x + tc3.y + be0);
        ((float4*)ekey_out)[q] = make_float4(e0, e1, e2, e3);
        atomicAdd(&binK[g0], e0); atomicAdd(&binE[g0], 1.0f - e0);
        if (e0 > 0.f) atomicAdd(&binZ[g0], 1.0f);
        atomicAdd(&binC[g0], 1.0f);
        atomicAdd(&binK[g1], e1); atomicAdd(&binE[g1], 1.0f - e1);
        if (e1 > 0.f) atomicAdd(&binZ[g1], 1.0f);
        atomicAdd(&binC[g1], 1.0f);
        atomicAdd(&binK[g2], e2); atomicAdd(&binE[g2], 1.0f - e2);
        if (e2 > 0.f) atomicAdd(&binZ[g2], 1.0f);
        atomicAdd(&binC[g2], 1.0f);
        atomicAdd(&binK[g3], e3); atomicAdd(&binE[g3], 1.0f - e3);
        if (e3 > 0.f) atomicAdd(&binZ[g3], 1.0f);
        atomicAdd(&binC[g3], 1.0f);
    }
    __syncthreads();
    for (int g = tid; g < NG; g += 256) {
        if (binC[g] != 0.f) {
            unsafeAtomicAdd(&accE[g], binK[g]);
            unsafeAtomicAdd(&accE[NG + g], binE[g]);
            unsafeAtomicAdd(&accE[2 * NG + g], binZ[g]);
            unsafeAtomicAdd(&accE[3 * NG + g], binC[g]);
        }
    }
    __syncthreads();
    if (tid == 0) {
        __threadfence();
        int old = atomicAdd(ctr, 1);
        isLast = (old == (int)gridDim.x - 1);
    }
    __syncthreads();
    if (isLast) {
        __threadfence();
        for (int g = tid; g < NG; g += 256) {
            out[O_NKN + g] = accN[g] + 1e-8f;
            out[O_NEN + g] = accN[NG + g] + 1e-8f;
            out[O_EKN + g] = accE[g] + 1e-8f;
            out[O_EEN + g] = accE[NG + g] + 1e-8f;
            out[O_NZN + g] = accN[2 * NG + g] / accN[3 * NG + g];
            out[O_NZE + g] = accE[2 * NG + g] / accE[3 * NG + g];
        }
    }
}

extern "C" void kernel_launch(void* const* d_in, const int* in_sizes, int n_in,
                              void* d_out, int out_size, void* d_ws, size_t ws_size,
                              hipStream_t stream) {
    const float* x     = (const float*)d_in[0];
    const int*   ei    = (const int*)d_in[1];
    const int*   batch = (const int*)d_in[2];
    const float* W     = (const float*)d_in[4];
    const float* bh    = (const float*)d_in[5];   // [2][128]
    const float* gamma = (const float*)d_in[6];
    const float* beta  = (const float*)d_in[7];
    const float* mean  = (const float*)d_in[8];
    const float* var   = (const float*)d_in[9];
    const float* We    = (const float*)d_in[10];
    const float* be    = (const float*)d_in[11];
    const float* Wn    = (const float*)d_in[12];
    const float* bnb   = (const float*)d_in[13];

    float* ws  = (float*)d_ws;
    float* out = (float*)d_out;

    float*        accN = ws + OFF_ACCN;
    float*        accE = ws + OFF_ACCE;
    int*          ctr  = (int*)(ws + OFF_CTR);
    float*        dis  = ws + OFF_DIS;
    int*          cnt  = (int*)(ws + OFF_CNT);
    int*          colp = (int*)(ws + OFF_COLP);
    int*          ends = (int*)(ws + OFF_ENDS);
    int*          bsum = (int*)(ws + OFF_BSUM);
    float*        bp   = ws + OFF_BP;
    bf16_t*       Wpt  = (bf16_t*)(ws + OFF_WPT);
    int*          PR   = (int*)(ws + OFF_PR);
    int*          PC   = (int*)(ws + OFF_PC);
    unsigned int* srcs = (unsigned int*)(ws + OFF_SRCS);  // aliases PR
    float4*       tb   = (float4*)(ws + OFF_TB);          // after srcs, PR region
    bf16_t*       hbfA = (bf16_t*)(ws + OFF_HBFA);
    bf16_t*       hbfB = (bf16_t*)(ws + OFF_HBFB);

    hipMemsetAsync(d_ws, 0, (size_t)ZERO_FLOATS * sizeof(float), stream);

    // CSR count + prep_w (merged)
    count_prep<<<dim3(2, NCHUNK, 3), 256, RSZC * sizeof(int), stream>>>(
        ei, PR, PC, W, gamma, beta, mean, var, Wpt, bp);
    const int NB = (NN + 255) / 256;  // 196
    csr_mid<<<NB, 256, 0, stream>>>(PR, PC, dis, cnt, colp, bsum);
    scan3<<<NB, 256, 0, stream>>>(colp, bsum, cnt, ends);

    const int GB = (NN + 63) / 64;  // 782
    // MERGED: CSR fill (blocks 0-255) || fused GEMM layers 0+1 (blocks 256-1037)
    fill_gemm01<<<256 + GB, 256, 81920, stream>>>(ei, colp, PC, dis, srcs,
                                                  x, Wpt, Wpt + D * D, bp, bp + D, hbfB);
    // propagate 1 + fused relu(v + bh0): hbfA = bf16(relu(P(hbfB) + bh0))
    prop_gather<0><<<12500, 256, 0, stream>>>(colp, ends, srcs, dis, hbfB, hbfA, bh);
    // layer 2 linear: hbfB = bf16(hbfA @ Wp2 + bp2)
    gemm2<<<GB, 256, 0, stream>>>(hbfA, Wpt + 2 * D * D, bp + 2 * D, hbfB);
    // propagate 2: hbfA = bf16(P(hbfB))  (node_rep)
    prop_gather<1><<<12500, 256, 0, stream>>>(colp, ends, srcs, dis, hbfB, hbfA, nullptr);

    node_kernel<<<512, 256, 0, stream>>>(hbfA, bh + D, We, Wn, bnb, batch,
                                         out + O_NKEY, tb, accN);
    edge_final<<<EDGE_BLOCKS, 256, 0, stream>>>(ei, tb, be, out + O_EKEY,
                                                accE, accN, ctr, out);
}

// Round 14
// 202.874 us; speedup vs baseline: 1.2426x; 1.0102x over previous
//
#include <hip/hip_runtime.h>
#include <cstddef>
#include <cstring>

#define NN 50000
#define NNP 50048
#define NE 800000
#define D 128
#define NG 512
#define BN_EPS 1e-5f
#define RSZC 25000    // count: nodes per range (2 ranges, 100 KB dyn LDS)
#define RSZF 12500    // fill: nodes per range (4 ranges, 50 KB LDS)
#define NCHUNK 64
#define CSZ 12500     // edges per chunk
#define EDGE_BLOCKS 256
#define NB 196        // csr_mid blocks = ceil(NN/256)

typedef __bf16 bf16_t;
typedef __bf16 bf16x8 __attribute__((ext_vector_type(8)));
typedef float f32x4 __attribute__((ext_vector_type(4)));

// ---- workspace layout (float offsets) ----
#define OFF_ACCN 0            // float[4*512]
#define OFF_ACCE 2048         // float[4*512]
#define OFF_CTR  4096         // int[1]
#define ZERO_FLOATS 4160      // zeroed region = [0, here), zeroed by count_prep
#define OFF_DIS  4160         // float[50048]
#define OFF_CNT  54208        // int[50048]
#define OFF_COLP 104256      // int[50048] final colp
#define OFF_ENDS 154304      // int[50048]
#define OFF_BSUM 204352      // int[256]
#define OFF_COLPL 204800     // int[50048] block-local exclusive
#define OFF_BP   304896      // float[3*128 padded]
#define OFF_WPT  305408      // bf16[3*128*128] (24576 floats)
#define OFF_PR   329984      // int[64][50048] = 3203072
#define OFF_PC   3533056     // int[64][50048] = 3203072 (CPS after csr_mid)
#define OFF_SRCS OFF_PR      // uint[800000], aliases PR (dead after csr_mid)
#define OFF_TB   1129984     // float4[50048], after srcs in PR region
#define OFF_HBFA 7536128     // bf16[50048*128] (3203072 floats)
#define OFF_HBFB 10739200    // bf16[50048*128]

// ---- output layout (float offsets in d_out) ----
#define O_NKEY 0
#define O_EKEY 50000
#define O_NKN  850000
#define O_NEN  850512
#define O_EKN  851024
#define O_EEN  851536
#define O_NZN  852048
#define O_NZE  852560

__device__ __forceinline__ float sigmoidf(float x) {
    return 1.0f / (1.0f + expf(-x));
}

__device__ __forceinline__ unsigned short f2bf_bits(float f) {
    bf16_t h = (bf16_t)f;
    unsigned short u;
    __builtin_memcpy(&u, &h, 2);
    return u;
}

__device__ __forceinline__ float bf_lo(unsigned int u) {
    return __uint_as_float(u << 16);
}
__device__ __forceinline__ float bf_hi(unsigned int u) {
    return __uint_as_float(u & 0xFFFF0000u);
}

// count histograms (2 ranges x 64 chunks x 2 dirs); z==2 carries prep_w + ws-zeroing
__global__ __launch_bounds__(256) void count_prep(const int* __restrict__ ei,
                                                  int* __restrict__ PR,
                                                  int* __restrict__ PC,
                                                  const float* __restrict__ W,
                                                  const float* __restrict__ gamma,
                                                  const float* __restrict__ beta,
                                                  const float* __restrict__ mean,
                                                  const float* __restrict__ var,
                                                  bf16_t* __restrict__ Wpt,
                                                  float* __restrict__ bp,
                                                  float* __restrict__ zbase) {
    const int tid = threadIdx.x;
    if (blockIdx.z == 2) {
        if (blockIdx.x == 0 && blockIdx.y < 3 && tid < D) {
            int l = blockIdx.y;
            int j = tid;
            float acc = 0.f;
            for (int k = 0; k < D; ++k) {
                float a = gamma[l * D + k] * rsqrtf(var[l * D + k] + BN_EPS);
                float c = beta[l * D + k] - mean[l * D + k] * a;
                float w = W[l * D * D + k * D + j];
                Wpt[l * D * D + j * D + k] = (bf16_t)(a * w);
                acc = fmaf(c, w, acc);
            }
            bp[l * D + j] = acc;
        } else if (blockIdx.x == 1 && blockIdx.y == 0) {
            for (int i = tid; i < ZERO_FLOATS; i += 256) zbase[i] = 0.f;
        }
        return;
    }
    extern __shared__ int hist[];
    const int r = blockIdx.x, p = blockIdx.y, dirz = blockIdx.z;
    for (int i = tid; i < RSZC; i += 256) hist[i] = 0;
    __syncthreads();
    const int base = r * RSZC;
    const int4* ids = (const int4*)(ei + dirz * NE + p * CSZ);
    for (int i = tid; i < CSZ / 4; i += 256) {
        int4 v = ids[i];
        int d0 = v.x - base, d1 = v.y - base, d2 = v.z - base, d3 = v.w - base;
        if ((unsigned)d0 < RSZC) atomicAdd(&hist[d0], 1);
        if ((unsigned)d1 < RSZC) atomicAdd(&hist[d1], 1);
        if ((unsigned)d2 < RSZC) atomicAdd(&hist[d2], 1);
        if ((unsigned)d3 < RSZC) atomicAdd(&hist[d3], 1);
    }
    __syncthreads();
    int* dst = (dirz == 0 ? PR : PC) + p * NNP + base;
    for (int i = tid; i < RSZC; i += 256) dst[i] = hist[i];
}

// fused: rowsum->dis, colscan->cnt + per-chunk offsets in PC, block-local scan.
// Writes colpL (LOCAL exclusive) — final colp/ends produced in the next dispatch.
__global__ void csr_mid(const int* __restrict__ PR, int* __restrict__ PC,
                        float* __restrict__ dis, int* __restrict__ cnt,
                        int* __restrict__ colpL, int* __restrict__ bsum) {
    __shared__ int s[256];
    int t = threadIdx.x;
    int i = blockIdx.x * 256 + t;
    int run = 0;
    if (i < NN) {
        int dg = 0;
#pragma unroll 8
        for (int k = 0; k < NCHUNK; ++k) dg += PR[k * NNP + i];
        dis[i] = rsqrtf((float)(dg + 1));
        for (int k = 0; k < NCHUNK; ++k) {
            int v = PC[k * NNP + i];
            PC[k * NNP + i] = run;
            run += v;
        }
        cnt[i] = run;
    }
    s[t] = run;
    __syncthreads();
    for (int o = 1; o < 256; o <<= 1) {
        int add = (t >= o) ? s[t - o] : 0;
        __syncthreads();
        s[t] += add;
        __syncthreads();
    }
    if (i < NN) colpL[i] = s[t] - run;  // local exclusive
    if (t == 255) bsum[blockIdx.x] = s[255];
}

// MERGED heterogeneous dispatch, 3 independent block classes (all read only
// csr_mid/count_prep outputs — no intra-dispatch dependencies):
//   [0,196):    scan-class -> final colp/ends (for the props)
//   [196,452):  CSR fill   -> srcs (reconstructs offsets from colpL + bsum-prefix)
//   [452,1234): fused GEMM layers 0+1
__global__ __launch_bounds__(256) void fill_gemm01(
    const int* __restrict__ ei, const int* __restrict__ colpL,
    const int* __restrict__ bsum, const int* __restrict__ cnt,
    int* __restrict__ colp, int* __restrict__ ends,
    const int* __restrict__ CPS, const float* __restrict__ dis,
    unsigned int* __restrict__ srcs,
    const float* __restrict__ X, const bf16_t* __restrict__ Bt0,
    const bf16_t* __restrict__ Bt1, const float* __restrict__ bias0,
    const float* __restrict__ bias1, bf16_t* __restrict__ out) {
    extern __shared__ __align__(16) unsigned short smem[];
    const int bid = blockIdx.x;
    const int tid = threadIdx.x;

    if (bid < NB) {
        // ---- scan-class: colp[i] = colpL[i] + sum(bsum[0..bid)); ends = colp+cnt
        int* s = (int*)smem;
        s[tid] = (tid < bid) ? bsum[tid] : 0;
        __syncthreads();
        for (int o = 128; o; o >>= 1) {
            if (tid < o) s[tid] += s[tid + o];
            __syncthreads();
        }
        int boff = s[0];
        int i = bid * 256 + tid;
        if (i < NN) {
            int v = colpL[i] + boff;
            colp[i] = v;
            ends[i] = v + cnt[i];
        }
        return;
    }

    if (bid < NB + 256) {
        // ---- CSR fill: packed entries src|bf16(dis[src])<<16 ----
        int* curs = (int*)smem;          // RSZF ints = 50000 B
        int* pb = curs + RSZF;           // 256 ints: exclusive prefix of bsum
        const int fb = bid - NB;
        const int r = fb & 3, p = fb >> 2;
        const int base = r * RSZF;
        {   // exclusive prefix scan of bsum (196 entries) into pb
            int v = (tid < NB) ? bsum[tid] : 0;
            pb[tid] = v;
            __syncthreads();
            for (int o = 1; o < 256; o <<= 1) {
                int add = (tid >= o) ? pb[tid - o] : 0;
                __syncthreads();
                pb[tid] += add;
                __syncthreads();
            }
            int ex = pb[tid] - v;
            __syncthreads();
            pb[tid] = ex;
            __syncthreads();
        }
        for (int i = tid; i < RSZF; i += 256) {
            int g = base + i;
            curs[i] = colpL[g] + pb[g >> 8] + CPS[p * NNP + g];
        }
        __syncthreads();
        const int4* rows = (const int4*)(ei + p * CSZ);
        const int4* cols = (const int4*)(ei + NE + p * CSZ);
        for (int i = tid; i < CSZ / 4; i += 256) {
            int4 rv = rows[i];
            int4 cv = cols[i];
            int d;
            d = cv.x - base;
            if ((unsigned)d < RSZF)
                srcs[atomicAdd(&curs[d], 1)] =
                    (unsigned int)rv.x | ((unsigned int)f2bf_bits(dis[rv.x]) << 16);
            d = cv.y - base;
            if ((unsigned)d < RSZF)
                srcs[atomicAdd(&curs[d], 1)] =
                    (unsigned int)rv.y | ((unsigned int)f2bf_bits(dis[rv.y]) << 16);
            d = cv.z - base;
            if ((unsigned)d < RSZF)
                srcs[atomicAdd(&curs[d], 1)] =
                    (unsigned int)rv.z | ((unsigned int)f2bf_bits(dis[rv.z]) << 16);
            d = cv.w - base;
            if ((unsigned)d < RSZF)
                srcs[atomicAdd(&curs[d], 1)] =
                    (unsigned int)rv.w | ((unsigned int)f2bf_bits(dis[rv.w]) << 16);
        }
        return;
    }

    // ---- fused GEMM layers 0+1, B0/B1/h0 in LDS (XOR-swizzled 16B units) ----
    unsigned short* Bs0 = smem;             // 32 KB
    unsigned short* Bs1 = smem + 16384;     // 32 KB
    unsigned short* As  = smem + 32768;     // 16 KB
    const int wv = tid >> 6;
    const int lane = tid & 63;
    const int l15 = lane & 15;
    const int l4 = lane >> 4;
    const int row0 = (bid - NB - 256) * 64;

    for (int q = tid; q < 2048; q += 256) {
        int r = q >> 4, u = q & 15;
        int us = (u ^ (r & 7)) * 8;
        *(uint4*)&Bs0[r * 128 + us] = *(const uint4*)(Bt0 + r * D + u * 8);
        *(uint4*)&Bs1[r * 128 + us] = *(const uint4*)(Bt1 + r * D + u * 8);
    }

    bf16x8 afrag[4];
    {
        int r = row0 + wv * 16 + l15;
        int rc = (r < NN) ? r : (NN - 1);
#pragma unroll
        for (int kk = 0; kk < 4; ++kk) {
            int off = rc * D + kk * 32 + l4 * 8;
            float4 f0 = *(const float4*)(X + off);
            float4 f1 = *(const float4*)(X + off + 4);
            bf16x8 a;
            a[0] = (bf16_t)f0.x; a[1] = (bf16_t)f0.y;
            a[2] = (bf16_t)f0.z; a[3] = (bf16_t)f0.w;
            a[4] = (bf16_t)f1.x; a[5] = (bf16_t)f1.y;
            a[6] = (bf16_t)f1.z; a[7] = (bf16_t)f1.w;
            afrag[kk] = a;
        }
    }
    __syncthreads();

    const int rsw = l15 & 7;
    f32x4 acc[8];
#pragma unroll
    for (int n = 0; n < 8; ++n) acc[n] = (f32x4){0.f, 0.f, 0.f, 0.f};
#pragma unroll
    for (int n = 0; n < 8; ++n) {
#pragma unroll
        for (int kk = 0; kk < 4; ++kk) {
            bf16x8 bfrag = *(const bf16x8*)&Bs0[(n * 16 + l15) * 128 + ((kk * 4 + l4) ^ rsw) * 8];
            acc[n] = __builtin_amdgcn_mfma_f32_16x16x32_bf16(afrag[kk], bfrag, acc[n], 0, 0, 0);
        }
    }
#pragma unroll
    for (int n = 0; n < 8; ++n) {
        int col = n * 16 + l15;
        float bv = bias0[col];
#pragma unroll
        for (int r = 0; r < 4; ++r) {
            int rl = wv * 16 + l4 * 4 + r;
            float v = fmaxf(acc[n][r] + bv, 0.f);
            int cs = ((col >> 3) ^ (rl & 7));
            As[rl * 128 + cs * 8 + (col & 7)] = f2bf_bits(v);
        }
    }
    __syncthreads();

    const int rl = wv * 16 + l15;
    bf16x8 af2[4];
#pragma unroll
    for (int kk = 0; kk < 4; ++kk) {
        int cs = (kk * 4 + l4) ^ (rl & 7);
        af2[kk] = *(const bf16x8*)&As[rl * 128 + cs * 8];
    }
#pragma unroll
    for (int n = 0; n < 8; ++n) acc[n] = (f32x4){0.f, 0.f, 0.f, 0.f};
#pragma unroll
    for (int n = 0; n < 8; ++n) {
#pragma unroll
        for (int kk = 0; kk < 4; ++kk) {
            bf16x8 bfrag = *(const bf16x8*)&Bs1[(n * 16 + l15) * 128 + ((kk * 4 + l4) ^ rsw) * 8];
            acc[n] = __builtin_amdgcn_mfma_f32_16x16x32_bf16(af2[kk], bfrag, acc[n], 0, 0, 0);
        }
    }
#pragma unroll
    for (int n = 0; n < 8; ++n) {
        int col = n * 16 + l15;
        float bv = bias1[col];
#pragma unroll
        for (int r = 0; r < 4; ++r) {
            int row = row0 + wv * 16 + l4 * 4 + r;
            if (row < NN) out[(size_t)row * D + col] = (bf16_t)(acc[n][r] + bv);
        }
    }
}

// layer-2 GEMM with B staged in LDS
__global__ __launch_bounds__(256) void gemm2(const bf16_t* __restrict__ A,
                                             const bf16_t* __restrict__ Bt,
                                             const float* __restrict__ bias,
                                             bf16_t* __restrict__ out) {
    __shared__ __align__(16) unsigned short Bs[128 * 128];
    const int tid = threadIdx.x;
    const int wv = tid >> 6;
    const int lane = tid & 63;
    const int l15 = lane & 15;
    const int l4 = lane >> 4;
    const int row0 = blockIdx.x * 64 + wv * 16;

    for (int q = tid; q < 2048; q += 256) {
        int r = q >> 4, u = q & 15;
        *(uint4*)&Bs[r * 128 + (u ^ (r & 7)) * 8] = *(const uint4*)(Bt + r * D + u * 8);
    }

    bf16x8 afrag[4];
    {
        int r = row0 + l15;
        int rc = (r < NN) ? r : (NN - 1);
#pragma unroll
        for (int kk = 0; kk < 4; ++kk)
            afrag[kk] = *(const bf16x8*)(A + rc * D + kk * 32 + l4 * 8);
    }
    __syncthreads();

    const int rsw = l15 & 7;
    f32x4 acc[8];
#pragma unroll
    for (int n = 0; n < 8; ++n) acc[n] = (f32x4){0.f, 0.f, 0.f, 0.f};
#pragma unroll
    for (int n = 0; n < 8; ++n) {
#pragma unroll
        for (int kk = 0; kk < 4; ++kk) {
            bf16x8 bfrag = *(const bf16x8*)&Bs[(n * 16 + l15) * 128 + ((kk * 4 + l4) ^ rsw) * 8];
            acc[n] = __builtin_amdgcn_mfma_f32_16x16x32_bf16(afrag[kk], bfrag, acc[n], 0, 0, 0);
        }
    }
#pragma unroll
    for (int n = 0; n < 8; ++n) {
        int col = n * 16 + l15;
        float bv = bias[col];
#pragma unroll
        for (int r = 0; r < 4; ++r) {
            int row = row0 + l4 * 4 + r;
            if (row < NN) out[(size_t)row * D + col] = (bf16_t)(acc[n][r] + bv);
        }
    }
}

// gather propagate: one wave per node, unroll x4, packed srcs.
// POST 0: out bf16 = relu(v + bias);  POST 1: out bf16 = v
template <int POST>
__global__ __launch_bounds__(256) void prop_gather(
    const int* __restrict__ colp, const int* __restrict__ ends,
    const unsigned int* __restrict__ srcs, const float* __restrict__ dis,
    const bf16_t* __restrict__ hin, bf16_t* __restrict__ hout,
    const float* __restrict__ bias) {
    int n = blockIdx.x * 4 + (threadIdx.x >> 6);
    n = __builtin_amdgcn_readfirstlane(n);   // wave-uniform: scalarize CSR chain
    int lane = threadIdx.x & 63;
    if (n >= NN) return;
    const int start = colp[n];
    const int end = ends[n];
    const float dn = dis[n];
    unsigned int u = ((const unsigned int*)(hin + (size_t)n * D))[lane];
    float ax = dn * bf_lo(u), ay = dn * bf_hi(u);
    int i = start;
    for (; i + 3 < end; i += 4) {
        unsigned int e0 = srcs[i], e1 = srcs[i + 1], e2 = srcs[i + 2], e3 = srcs[i + 3];
        unsigned int u0 = ((const unsigned int*)(hin + (size_t)(e0 & 0xFFFFu) * D))[lane];
        unsigned int u1 = ((const unsigned int*)(hin + (size_t)(e1 & 0xFFFFu) * D))[lane];
        unsigned int u2 = ((const unsigned int*)(hin + (size_t)(e2 & 0xFFFFu) * D))[lane];
        unsigned int u3 = ((const unsigned int*)(hin + (size_t)(e3 & 0xFFFFu) * D))[lane];
        float w0 = bf_hi(e0), w1 = bf_hi(e1), w2 = bf_hi(e2), w3 = bf_hi(e3);
        ax = fmaf(w0, bf_lo(u0), ax); ay = fmaf(w0, bf_hi(u0), ay);
        ax = fmaf(w1, bf_lo(u1), ax); ay = fmaf(w1, bf_hi(u1), ay);
        ax = fmaf(w2, bf_lo(u2), ax); ay = fmaf(w2, bf_hi(u2), ay);
        ax = fmaf(w3, bf_lo(u3), ax); ay = fmaf(w3, bf_hi(u3), ay);
    }
    for (; i < end; ++i) {
        unsigned int e0 = srcs[i];
        unsigned int u0 = ((const unsigned int*)(hin + (size_t)(e0 & 0xFFFFu) * D))[lane];
        float w0 = bf_hi(e0);
        ax = fmaf(w0, bf_lo(u0), ax); ay = fmaf(w0, bf_hi(u0), ay);
    }
    float vx = dn * ax, vy = dn * ay;
    if (POST == 0) {
        float2 bb = ((const float2*)bias)[lane];
        vx = fmaxf(vx + bb.x, 0.f);
        vy = fmaxf(vy + bb.y, 0.f);
    }
    unsigned int pk = (unsigned int)f2bf_bits(vx) | ((unsigned int)f2bf_bits(vy) << 16);
    ((unsigned int*)(hout + (size_t)n * D))[lane] = pk;
}

// node head on bf16 node_rep; writes packed tb = (t1, t2, batch, 0) per node
__global__ __launch_bounds__(256) void node_kernel(
    const bf16_t* __restrict__ h, const float* __restrict__ bh1,
    const float* __restrict__ We, const float* __restrict__ Wn,
    const float* __restrict__ bnb, const int* __restrict__ batch,
    float* __restrict__ nkey_out, float4* __restrict__ tb,
    float* __restrict__ accN) {
    __shared__ float binK[NG], binE[NG], binZ[NG], binC[NG];
    const int tid = threadIdx.x;
    for (int i = tid; i < NG; i += 256) { binK[i] = 0.f; binE[i] = 0.f; binZ[i] = 0.f; binC[i] = 0.f; }
    __syncthreads();

    const int CHUNK = 98;
    int start = blockIdx.x * CHUNK;
    int end = min(start + CHUNK, NN);
    int sub = tid >> 5;
    int l32 = tid & 31;
    float bnb0 = bnb[0];

    float4 w1 = ((const float4*)We)[l32];
    float4 w2 = ((const float4*)(We + D))[l32];
    float4 wn = ((const float4*)Wn)[l32];
    float4 bb = ((const float4*)bh1)[l32];

    for (int n = start + sub; n < end; n += 8) {
        uint2 pk = ((const uint2*)(h + (size_t)n * D))[l32];
        float v0 = bf_lo(pk.x) + bb.x;
        float v1 = bf_hi(pk.x) + bb.y;
        float v2 = bf_lo(pk.y) + bb.z;
        float v3 = bf_hi(pk.y) + bb.w;
        float s1 = v0 * w1.x + v1 * w1.y + v2 * w1.z + v3 * w1.w;
        float s2 = v0 * w2.x + v1 * w2.y + v2 * w2.z + v3 * w2.w;
        float s3 = v0 * wn.x + v1 * wn.y + v2 * wn.z + v3 * wn.w;
        for (int o = 16; o; o >>= 1) {
            s1 += __shfl_xor(s1, o);
            s2 += __shfl_xor(s2, o);
            s3 += __shfl_xor(s3, o);
        }
        if (l32 == 0) {
            float nk = sigmoidf(s3 + bnb0);
            nkey_out[n] = nk;
            int g = batch[n];
            tb[n] = make_float4(s1, s2, __int_as_float(g), 0.f);
            atomicAdd(&binK[g], nk);
            atomicAdd(&binE[g], 1.0f - nk);
            if (nk > 0.f) atomicAdd(&binZ[g], 1.0f);
            atomicAdd(&binC[g], 1.0f);
        }
    }
    __syncthreads();
    if (start < NN) {
        int glo = batch[start];
        int ghi = batch[end - 1];
        for (int g = glo + tid; g <= ghi; g += 256) {
            unsafeAtomicAdd(&accN[g], binK[g]);
            unsafeAtomicAdd(&accN[NG + g], binE[g]);
            unsafeAtomicAdd(&accN[2 * NG + g], binZ[g]);
            unsafeAtomicAdd(&accN[3 * NG + g], binC[g]);
        }
    }
}

// edge head + inlined final reduction; tb packs (t1,t2,batch) -> 2 x 16B gathers/edge
__global__ __launch_bounds__(256) void edge_final(
    const int* __restrict__ ei, const float4* __restrict__ tb,
    const float* __restrict__ be, float* __restrict__ ekey_out,
    float* __restrict__ accE, const float* __restrict__ accN,
    int* __restrict__ ctr, float* __restrict__ out) {
    __shared__ float binK[NG], binE[NG], binZ[NG], binC[NG];
    __shared__ int isLast;
    const int tid = threadIdx.x;
    for (int i = tid; i < NG; i += 256) { binK[i] = 0.f; binE[i] = 0.f; binZ[i] = 0.f; binC[i] = 0.f; }
    __syncthreads();
    float be0 = be[0];
    int stride4 = gridDim.x * 256;
    for (int q = blockIdx.x * 256 + tid; q < NE / 4; q += stride4) {
        int4 r4 = ((const int4*)ei)[q];
        int4 c4 = ((const int4*)(ei + NE))[q];
        float4 tr0 = tb[r4.x], tr1 = tb[r4.y], tr2 = tb[r4.z], tr3 = tb[r4.w];
        float4 tc0 = tb[c4.x], tc1 = tb[c4.y], tc2 = tb[c4.z], tc3 = tb[c4.w];
        int g0 = __float_as_int(tr0.z), g1 = __float_as_int(tr1.z);
        int g2 = __float_as_int(tr2.z), g3 = __float_as_int(tr3.z);
        float e0 = sigmoidf(tr0.x + tc0.y + be0);
        float e1 = sigmoidf(tr1.x + tc1.y + be0);
        float e2 = sigmoidf(tr2.x + tc2.y + be0);
        float e3 = sigmoidf(tr3.x + tc3.y + be0);
        ((float4*)ekey_out)[q] = make_float4(e0, e1, e2, e3);
        atomicAdd(&binK[g0], e0); atomicAdd(&binE[g0], 1.0f - e0);
        if (e0 > 0.f) atomicAdd(&binZ[g0], 1.0f);
        atomicAdd(&binC[g0], 1.0f);
        atomicAdd(&binK[g1], e1); atomicAdd(&binE[g1], 1.0f - e1);
        if (e1 > 0.f) atomicAdd(&binZ[g1], 1.0f);
        atomicAdd(&binC[g1], 1.0f);
        atomicAdd(&binK[g2], e2); atomicAdd(&binE[g2], 1.0f - e2);
        if (e2 > 0.f) atomicAdd(&binZ[g2], 1.0f);
        atomicAdd(&binC[g2], 1.0f);
        atomicAdd(&binK[g3], e3); atomicAdd(&binE[g3], 1.0f - e3);
        if (e3 > 0.f) atomicAdd(&binZ[g3], 1.0f);
        atomicAdd(&binC[g3], 1.0f);
    }
    __syncthreads();
    for (int g = tid; g < NG; g += 256) {
        if (binC[g] != 0.f) {
            unsafeAtomicAdd(&accE[g], binK[g]);
            unsafeAtomicAdd(&accE[NG + g], binE[g]);
            unsafeAtomicAdd(&accE[2 * NG + g], binZ[g]);
            unsafeAtomicAdd(&accE[3 * NG + g], binC[g]);
        }
    }
    __syncthreads();
    if (tid == 0) {
        __threadfence();
        int old = atomicAdd(ctr, 1);
        isLast = (old == (int)gridDim.x - 1);
    }
    __syncthreads();
    if (isLast) {
        __threadfence();
        for (int g = tid; g < NG; g += 256) {
            out[O_NKN + g] = accN[g] + 1e-8f;
            out[O_NEN + g] = accN[NG + g] + 1e-8f;
            out[O_EKN + g] = accE[g] + 1e-8f;
            out[O_EEN + g] = accE[NG + g] + 1e-8f;
            out[O_NZN + g] = accN[2 * NG + g] / accN[3 * NG + g];
            out[O_NZE + g] = accE[2 * NG + g] / accE[3 * NG + g];
        }
    }
}

extern "C" void kernel_launch(void* const* d_in, const int* in_sizes, int n_in,
                              void* d_out, int out_size, void* d_ws, size_t ws_size,
                              hipStream_t stream) {
    const float* x     = (const float*)d_in[0];
    const int*   ei    = (const int*)d_in[1];
    const int*   batch = (const int*)d_in[2];
    const float* W     = (const float*)d_in[4];
    const float* bh    = (const float*)d_in[5];   // [2][128]
    const float* gamma = (const float*)d_in[6];
    const float* beta  = (const float*)d_in[7];
    const float* mean  = (const float*)d_in[8];
    const float* var   = (const float*)d_in[9];
    const float* We    = (const float*)d_in[10];
    const float* be    = (const float*)d_in[11];
    const float* Wn    = (const float*)d_in[12];
    const float* bnb   = (const float*)d_in[13];

    float* ws  = (float*)d_ws;
    float* out = (float*)d_out;

    float*        accN  = ws + OFF_ACCN;
    float*        accE  = ws + OFF_ACCE;
    int*          ctr   = (int*)(ws + OFF_CTR);
    float*        dis   = ws + OFF_DIS;
    int*          cnt   = (int*)(ws + OFF_CNT);
    int*          colp  = (int*)(ws + OFF_COLP);
    int*          ends  = (int*)(ws + OFF_ENDS);
    int*          bsum  = (int*)(ws + OFF_BSUM);
    int*          colpL = (int*)(ws + OFF_COLPL);
    float*        bp    = ws + OFF_BP;
    bf16_t*       Wpt   = (bf16_t*)(ws + OFF_WPT);
    int*          PR    = (int*)(ws + OFF_PR);
    int*          PC    = (int*)(ws + OFF_PC);
    unsigned int* srcs  = (unsigned int*)(ws + OFF_SRCS);  // aliases PR
    float4*       tb    = (float4*)(ws + OFF_TB);          // after srcs, PR region
    bf16_t*       hbfA  = (bf16_t*)(ws + OFF_HBFA);
    bf16_t*       hbfB  = (bf16_t*)(ws + OFF_HBFB);

    // CSR count + prep_w + workspace zeroing (merged; no memset dispatch)
    count_prep<<<dim3(2, NCHUNK, 3), 256, RSZC * sizeof(int), stream>>>(
        ei, PR, PC, W, gamma, beta, mean, var, Wpt, bp, ws);
    csr_mid<<<NB, 256, 0, stream>>>(PR, PC, dis, cnt, colpL, bsum);

    const int GB = (NN + 63) / 64;  // 782
    // MERGED: scan-class (196) || CSR fill (256) || fused GEMM layers 0+1 (782)
    fill_gemm01<<<NB + 256 + GB, 256, 81920, stream>>>(
        ei, colpL, bsum, cnt, colp, ends, PC, dis, srcs,
        x, Wpt, Wpt + D * D, bp, bp + D, hbfB);
    // propagate 1 + fused relu(v + bh0): hbfA = bf16(relu(P(hbfB) + bh0))
    prop_gather<0><<<12500, 256, 0, stream>>>(colp, ends, srcs, dis, hbfB, hbfA, bh);
    // layer 2 linear: hbfB = bf16(hbfA @ Wp2 + bp2)
    gemm2<<<GB, 256, 0, stream>>>(hbfA, Wpt + 2 * D * D, bp + 2 * D, hbfB);
    // propagate 2: hbfA = bf16(P(hbfB))  (node_rep)
    prop_gather<1><<<12500, 256, 0, stream>>>(colp, ends, srcs, dis, hbfB, hbfA, nullptr);

    node_kernel<<<512, 256, 0, stream>>>(hbfA, bh + D, We, Wn, bnb, batch,
                                         out + O_NKEY, tb, accN);
    edge_final<<<EDGE_BLOCKS, 256, 0, stream>>>(ei, tb, be, out + O_EKEY,
                                                accE, accN, ctr, out);
}

// Round 15
// 198.119 us; speedup vs baseline: 1.2725x; 1.0240x over previous
//
#include <hip/hip_runtime.h>
#include <cstddef>
#include <cstring>

#define NN 50000
#define NNP 50048
#define NE 800000
#define D 128
#define NG 512
#define BN_EPS 1e-5f
#define RSZC 25000    // count: nodes per range (2 ranges, 100 KB dyn LDS)
#define RSZF 12500    // fill: nodes per range (4 ranges, 50 KB LDS)
#define NCHUNK 64
#define CSZ 12500     // edges per chunk
#define EDGE_BLOCKS 256
#define NB 196        // csr_mid blocks = ceil(NN/256)

typedef __bf16 bf16_t;
typedef __bf16 bf16x8 __attribute__((ext_vector_type(8)));
typedef float f32x4 __attribute__((ext_vector_type(4)));

// ---- workspace layout (float offsets) ----
#define OFF_ACCN 0            // float[4*512]
#define OFF_ACCE 2048         // float[4*512]
#define OFF_CTR  4096         // int[1]
#define ZERO_FLOATS 4160      // zeroed region = [0, here), zeroed by count_prep
#define OFF_DIS  4160         // float[50048]
#define OFF_CNT  54208        // int[50048]
#define OFF_COLP 104256      // int[50048] final colp
#define OFF_ENDS 154304      // int[50048]
#define OFF_BSUM 204352      // int[256]
#define OFF_COLPL 204800     // int[50048] block-local exclusive
#define OFF_BP   304896      // float[3*128 padded]
#define OFF_WPT  305408      // bf16[3*128*128] (24576 floats)
#define OFF_PR   329984      // int[64][50048] = 3203072
#define OFF_PC   3533056     // int[64][50048] = 3203072 (CPS after csr_mid)
#define OFF_SRCS OFF_PR      // uint[800000], aliases PR (dead after csr_mid)
#define OFF_TB   1129984     // float4[50048], after srcs in PR region
#define OFF_HBFA 7536128     // bf16[50048*128] (3203072 floats)
#define OFF_HBFB 10739200    // bf16[50048*128]

// ---- output layout (float offsets in d_out) ----
#define O_NKEY 0
#define O_EKEY 50000
#define O_NKN  850000
#define O_NEN  850512
#define O_EKN  851024
#define O_EEN  851536
#define O_NZN  852048
#define O_NZE  852560

__device__ __forceinline__ float sigmoidf(float x) {
    return 1.0f / (1.0f + expf(-x));
}

__device__ __forceinline__ unsigned short f2bf_bits(float f) {
    bf16_t h = (bf16_t)f;
    unsigned short u;
    __builtin_memcpy(&u, &h, 2);
    return u;
}

__device__ __forceinline__ float bf_lo(unsigned int u) {
    return __uint_as_float(u << 16);
}
__device__ __forceinline__ float bf_hi(unsigned int u) {
    return __uint_as_float(u & 0xFFFF0000u);
}

// count histograms (2 ranges x 64 chunks x 2 dirs); z==2 carries prep_w + ws-zeroing
__global__ __launch_bounds__(256) void count_prep(const int* __restrict__ ei,
                                                  int* __restrict__ PR,
                                                  int* __restrict__ PC,
                                                  const float* __restrict__ W,
                                                  const float* __restrict__ gamma,
                                                  const float* __restrict__ beta,
                                                  const float* __restrict__ mean,
                                                  const float* __restrict__ var,
                                                  bf16_t* __restrict__ Wpt,
                                                  float* __restrict__ bp,
                                                  float* __restrict__ zbase) {
    const int tid = threadIdx.x;
    if (blockIdx.z == 2) {
        if (blockIdx.x == 0 && blockIdx.y < 3 && tid < D) {
            int l = blockIdx.y;
            int j = tid;
            float acc = 0.f;
            for (int k = 0; k < D; ++k) {
                float a = gamma[l * D + k] * rsqrtf(var[l * D + k] + BN_EPS);
                float c = beta[l * D + k] - mean[l * D + k] * a;
                float w = W[l * D * D + k * D + j];
                Wpt[l * D * D + j * D + k] = (bf16_t)(a * w);
                acc = fmaf(c, w, acc);
            }
            bp[l * D + j] = acc;
        } else if (blockIdx.x == 1 && blockIdx.y == 0) {
            for (int i = tid; i < ZERO_FLOATS; i += 256) zbase[i] = 0.f;
        }
        return;
    }
    extern __shared__ int hist[];
    const int r = blockIdx.x, p = blockIdx.y, dirz = blockIdx.z;
    for (int i = tid; i < RSZC; i += 256) hist[i] = 0;
    __syncthreads();
    const int base = r * RSZC;
    const int4* ids = (const int4*)(ei + dirz * NE + p * CSZ);
    for (int i = tid; i < CSZ / 4; i += 256) {
        int4 v = ids[i];
        int d0 = v.x - base, d1 = v.y - base, d2 = v.z - base, d3 = v.w - base;
        if ((unsigned)d0 < RSZC) atomicAdd(&hist[d0], 1);
        if ((unsigned)d1 < RSZC) atomicAdd(&hist[d1], 1);
        if ((unsigned)d2 < RSZC) atomicAdd(&hist[d2], 1);
        if ((unsigned)d3 < RSZC) atomicAdd(&hist[d3], 1);
    }
    __syncthreads();
    int* dst = (dirz == 0 ? PR : PC) + p * NNP + base;
    for (int i = tid; i < RSZC; i += 256) dst[i] = hist[i];
}

// fused: rowsum->dis, colscan->cnt + per-chunk offsets in PC, block-local scan.
// Writes colpL (LOCAL exclusive) — final colp/ends produced in the next dispatch.
__global__ void csr_mid(const int* __restrict__ PR, int* __restrict__ PC,
                        float* __restrict__ dis, int* __restrict__ cnt,
                        int* __restrict__ colpL, int* __restrict__ bsum) {
    __shared__ int s[256];
    int t = threadIdx.x;
    int i = blockIdx.x * 256 + t;
    int run = 0;
    if (i < NN) {
        int dg = 0;
#pragma unroll 8
        for (int k = 0; k < NCHUNK; ++k) dg += PR[k * NNP + i];
        dis[i] = rsqrtf((float)(dg + 1));
        for (int k = 0; k < NCHUNK; ++k) {
            int v = PC[k * NNP + i];
            PC[k * NNP + i] = run;
            run += v;
        }
        cnt[i] = run;
    }
    s[t] = run;
    __syncthreads();
    for (int o = 1; o < 256; o <<= 1) {
        int add = (t >= o) ? s[t - o] : 0;
        __syncthreads();
        s[t] += add;
        __syncthreads();
    }
    if (i < NN) colpL[i] = s[t] - run;  // local exclusive
    if (t == 255) bsum[blockIdx.x] = s[255];
}

// MERGED heterogeneous dispatch, 3 independent block classes.
// GEMM class stages B0/B1 SEQUENTIALLY through one 32 KB buffer so dispatch
// dyn-LDS is ~51 KB (fill's need) -> 3 blocks/CU instead of 2.
//   [0,196):    scan-class -> final colp/ends (for the props)
//   [196,452):  CSR fill   -> srcs
//   [452,1234): fused GEMM layers 0+1
__global__ __launch_bounds__(256) void fill_gemm01(
    const int* __restrict__ ei, const int* __restrict__ colpL,
    const int* __restrict__ bsum, const int* __restrict__ cnt,
    int* __restrict__ colp, int* __restrict__ ends,
    const int* __restrict__ CPS, const float* __restrict__ dis,
    unsigned int* __restrict__ srcs,
    const float* __restrict__ X, const bf16_t* __restrict__ Bt0,
    const bf16_t* __restrict__ Bt1, const float* __restrict__ bias0,
    const float* __restrict__ bias1, bf16_t* __restrict__ out) {
    extern __shared__ __align__(16) unsigned short smem[];
    const int bid = blockIdx.x;
    const int tid = threadIdx.x;

    if (bid < NB) {
        // ---- scan-class: colp[i] = colpL[i] + sum(bsum[0..bid)); ends = colp+cnt
        int* s = (int*)smem;
        s[tid] = (tid < bid) ? bsum[tid] : 0;
        __syncthreads();
        for (int o = 128; o; o >>= 1) {
            if (tid < o) s[tid] += s[tid + o];
            __syncthreads();
        }
        int boff = s[0];
        int i = bid * 256 + tid;
        if (i < NN) {
            int v = colpL[i] + boff;
            colp[i] = v;
            ends[i] = v + cnt[i];
        }
        return;
    }

    if (bid < NB + 256) {
        // ---- CSR fill: packed entries src|bf16(dis[src])<<16 ----
        int* curs = (int*)smem;          // RSZF ints = 50000 B
        int* pb = curs + RSZF;           // 256 ints: exclusive prefix of bsum
        const int fb = bid - NB;
        const int r = fb & 3, p = fb >> 2;
        const int base = r * RSZF;
        {   // exclusive prefix scan of bsum (196 entries) into pb
            int v = (tid < NB) ? bsum[tid] : 0;
            pb[tid] = v;
            __syncthreads();
            for (int o = 1; o < 256; o <<= 1) {
                int add = (tid >= o) ? pb[tid - o] : 0;
                __syncthreads();
                pb[tid] += add;
                __syncthreads();
            }
            int ex = pb[tid] - v;
            __syncthreads();
            pb[tid] = ex;
            __syncthreads();
        }
        for (int i = tid; i < RSZF; i += 256) {
            int g = base + i;
            curs[i] = colpL[g] + pb[g >> 8] + CPS[p * NNP + g];
        }
        __syncthreads();
        const int4* rows = (const int4*)(ei + p * CSZ);
        const int4* cols = (const int4*)(ei + NE + p * CSZ);
        for (int i = tid; i < CSZ / 4; i += 256) {
            int4 rv = rows[i];
            int4 cv = cols[i];
            int d;
            d = cv.x - base;
            if ((unsigned)d < RSZF)
                srcs[atomicAdd(&curs[d], 1)] =
                    (unsigned int)rv.x | ((unsigned int)f2bf_bits(dis[rv.x]) << 16);
            d = cv.y - base;
            if ((unsigned)d < RSZF)
                srcs[atomicAdd(&curs[d], 1)] =
                    (unsigned int)rv.y | ((unsigned int)f2bf_bits(dis[rv.y]) << 16);
            d = cv.z - base;
            if ((unsigned)d < RSZF)
                srcs[atomicAdd(&curs[d], 1)] =
                    (unsigned int)rv.z | ((unsigned int)f2bf_bits(dis[rv.z]) << 16);
            d = cv.w - base;
            if ((unsigned)d < RSZF)
                srcs[atomicAdd(&curs[d], 1)] =
                    (unsigned int)rv.w | ((unsigned int)f2bf_bits(dis[rv.w]) << 16);
        }
        return;
    }

    // ---- fused GEMM layers 0+1; ONE 32 KB B buffer staged twice + 16 KB As ----
    unsigned short* Bs = smem;              // 32 KB (B0 then B1)
    unsigned short* As = smem + 16384;      // 16 KB (h0)
    const int wv = tid >> 6;
    const int lane = tid & 63;
    const int l15 = lane & 15;
    const int l4 = lane >> 4;
    const int row0 = (bid - NB - 256) * 64;

    // stage B0
    for (int q = tid; q < 2048; q += 256) {
        int r = q >> 4, u = q & 15;
        *(uint4*)&Bs[r * 128 + (u ^ (r & 7)) * 8] = *(const uint4*)(Bt0 + r * D + u * 8);
    }

    bf16x8 afrag[4];
    {
        int r = row0 + wv * 16 + l15;
        int rc = (r < NN) ? r : (NN - 1);
#pragma unroll
        for (int kk = 0; kk < 4; ++kk) {
            int off = rc * D + kk * 32 + l4 * 8;
            float4 f0 = *(const float4*)(X + off);
            float4 f1 = *(const float4*)(X + off + 4);
            bf16x8 a;
            a[0] = (bf16_t)f0.x; a[1] = (bf16_t)f0.y;
            a[2] = (bf16_t)f0.z; a[3] = (bf16_t)f0.w;
            a[4] = (bf16_t)f1.x; a[5] = (bf16_t)f1.y;
            a[6] = (bf16_t)f1.z; a[7] = (bf16_t)f1.w;
            afrag[kk] = a;
        }
    }
    __syncthreads();

    const int rsw = l15 & 7;
    f32x4 acc[8];
#pragma unroll
    for (int n = 0; n < 8; ++n) acc[n] = (f32x4){0.f, 0.f, 0.f, 0.f};
#pragma unroll
    for (int n = 0; n < 8; ++n) {
#pragma unroll
        for (int kk = 0; kk < 4; ++kk) {
            bf16x8 bfrag = *(const bf16x8*)&Bs[(n * 16 + l15) * 128 + ((kk * 4 + l4) ^ rsw) * 8];
            acc[n] = __builtin_amdgcn_mfma_f32_16x16x32_bf16(afrag[kk], bfrag, acc[n], 0, 0, 0);
        }
    }
    // epilogue h0 -> swizzled As
#pragma unroll
    for (int n = 0; n < 8; ++n) {
        int col = n * 16 + l15;
        float bv = bias0[col];
#pragma unroll
        for (int r = 0; r < 4; ++r) {
            int rl = wv * 16 + l4 * 4 + r;
            float v = fmaxf(acc[n][r] + bv, 0.f);
            int cs = ((col >> 3) ^ (rl & 7));
            As[rl * 128 + cs * 8 + (col & 7)] = f2bf_bits(v);
        }
    }
    __syncthreads();   // all Bs(B0) reads + As writes complete

    // restage Bs with B1; read h0 fragments from As concurrently
    for (int q = tid; q < 2048; q += 256) {
        int r = q >> 4, u = q & 15;
        *(uint4*)&Bs[r * 128 + (u ^ (r & 7)) * 8] = *(const uint4*)(Bt1 + r * D + u * 8);
    }
    const int rl = wv * 16 + l15;
    bf16x8 af2[4];
#pragma unroll
    for (int kk = 0; kk < 4; ++kk) {
        int cs = (kk * 4 + l4) ^ (rl & 7);
        af2[kk] = *(const bf16x8*)&As[rl * 128 + cs * 8];
    }
    __syncthreads();   // Bs(B1) staged

#pragma unroll
    for (int n = 0; n < 8; ++n) acc[n] = (f32x4){0.f, 0.f, 0.f, 0.f};
#pragma unroll
    for (int n = 0; n < 8; ++n) {
#pragma unroll
        for (int kk = 0; kk < 4; ++kk) {
            bf16x8 bfrag = *(const bf16x8*)&Bs[(n * 16 + l15) * 128 + ((kk * 4 + l4) ^ rsw) * 8];
            acc[n] = __builtin_amdgcn_mfma_f32_16x16x32_bf16(af2[kk], bfrag, acc[n], 0, 0, 0);
        }
    }
#pragma unroll
    for (int n = 0; n < 8; ++n) {
        int col = n * 16 + l15;
        float bv = bias1[col];
#pragma unroll
        for (int r = 0; r < 4; ++r) {
            int row = row0 + wv * 16 + l4 * 4 + r;
            if (row < NN) out[(size_t)row * D + col] = (bf16_t)(acc[n][r] + bv);
        }
    }
}

// layer-2 GEMM with B staged in LDS
__global__ __launch_bounds__(256) void gemm2(const bf16_t* __restrict__ A,
                                             const bf16_t* __restrict__ Bt,
                                             const float* __restrict__ bias,
                                             bf16_t* __restrict__ out) {
    __shared__ __align__(16) unsigned short Bs[128 * 128];
    const int tid = threadIdx.x;
    const int wv = tid >> 6;
    const int lane = tid & 63;
    const int l15 = lane & 15;
    const int l4 = lane >> 4;
    const int row0 = blockIdx.x * 64 + wv * 16;

    for (int q = tid; q < 2048; q += 256) {
        int r = q >> 4, u = q & 15;
        *(uint4*)&Bs[r * 128 + (u ^ (r & 7)) * 8] = *(const uint4*)(Bt + r * D + u * 8);
    }

    bf16x8 afrag[4];
    {
        int r = row0 + l15;
        int rc = (r < NN) ? r : (NN - 1);
#pragma unroll
        for (int kk = 0; kk < 4; ++kk)
            afrag[kk] = *(const bf16x8*)(A + rc * D + kk * 32 + l4 * 8);
    }
    __syncthreads();

    const int rsw = l15 & 7;
    f32x4 acc[8];
#pragma unroll
    for (int n = 0; n < 8; ++n) acc[n] = (f32x4){0.f, 0.f, 0.f, 0.f};
#pragma unroll
    for (int n = 0; n < 8; ++n) {
#pragma unroll
        for (int kk = 0; kk < 4; ++kk) {
            bf16x8 bfrag = *(const bf16x8*)&Bs[(n * 16 + l15) * 128 + ((kk * 4 + l4) ^ rsw) * 8];
            acc[n] = __builtin_amdgcn_mfma_f32_16x16x32_bf16(afrag[kk], bfrag, acc[n], 0, 0, 0);
        }
    }
#pragma unroll
    for (int n = 0; n < 8; ++n) {
        int col = n * 16 + l15;
        float bv = bias[col];
#pragma unroll
        for (int r = 0; r < 4; ++r) {
            int row = row0 + l4 * 4 + r;
            if (row < NN) out[(size_t)row * D + col] = (bf16_t)(acc[n][r] + bv);
        }
    }
}

// gather propagate: one wave per node, unroll x4, packed srcs.
// POST 0: out bf16 = relu(v + bias);  POST 1: out bf16 = v
template <int POST>
__global__ __launch_bounds__(256) void prop_gather(
    const int* __restrict__ colp, const int* __restrict__ ends,
    const unsigned int* __restrict__ srcs, const float* __restrict__ dis,
    const bf16_t* __restrict__ hin, bf16_t* __restrict__ hout,
    const float* __restrict__ bias) {
    int n = blockIdx.x * 4 + (threadIdx.x >> 6);
    n = __builtin_amdgcn_readfirstlane(n);   // wave-uniform: scalarize CSR chain
    int lane = threadIdx.x & 63;
    if (n >= NN) return;
    const int start = colp[n];
    const int end = ends[n];
    const float dn = dis[n];
    unsigned int u = ((const unsigned int*)(hin + (size_t)n * D))[lane];
    float ax = dn * bf_lo(u), ay = dn * bf_hi(u);
    int i = start;
    for (; i + 3 < end; i += 4) {
        unsigned int e0 = srcs[i], e1 = srcs[i + 1], e2 = srcs[i + 2], e3 = srcs[i + 3];
        unsigned int u0 = ((const unsigned int*)(hin + (size_t)(e0 & 0xFFFFu) * D))[lane];
        unsigned int u1 = ((const unsigned int*)(hin + (size_t)(e1 & 0xFFFFu) * D))[lane];
        unsigned int u2 = ((const unsigned int*)(hin + (size_t)(e2 & 0xFFFFu) * D))[lane];
        unsigned int u3 = ((const unsigned int*)(hin + (size_t)(e3 & 0xFFFFu) * D))[lane];
        float w0 = bf_hi(e0), w1 = bf_hi(e1), w2 = bf_hi(e2), w3 = bf_hi(e3);
        ax = fmaf(w0, bf_lo(u0), ax); ay = fmaf(w0, bf_hi(u0), ay);
        ax = fmaf(w1, bf_lo(u1), ax); ay = fmaf(w1, bf_hi(u1), ay);
        ax = fmaf(w2, bf_lo(u2), ax); ay = fmaf(w2, bf_hi(u2), ay);
        ax = fmaf(w3, bf_lo(u3), ax); ay = fmaf(w3, bf_hi(u3), ay);
    }
    for (; i < end; ++i) {
        unsigned int e0 = srcs[i];
        unsigned int u0 = ((const unsigned int*)(hin + (size_t)(e0 & 0xFFFFu) * D))[lane];
        float w0 = bf_hi(e0);
        ax = fmaf(w0, bf_lo(u0), ax); ay = fmaf(w0, bf_hi(u0), ay);
    }
    float vx = dn * ax, vy = dn * ay;
    if (POST == 0) {
        float2 bb = ((const float2*)bias)[lane];
        vx = fmaxf(vx + bb.x, 0.f);
        vy = fmaxf(vy + bb.y, 0.f);
    }
    unsigned int pk = (unsigned int)f2bf_bits(vx) | ((unsigned int)f2bf_bits(vy) << 16);
    ((unsigned int*)(hout + (size_t)n * D))[lane] = pk;
}

// node head on bf16 node_rep; writes packed tb = (t1, t2, batch, 0) per node
__global__ __launch_bounds__(256) void node_kernel(
    const bf16_t* __restrict__ h, const float* __restrict__ bh1,
    const float* __restrict__ We, const float* __restrict__ Wn,
    const float* __restrict__ bnb, const int* __restrict__ batch,
    float* __restrict__ nkey_out, float4* __restrict__ tb,
    float* __restrict__ accN) {
    __shared__ float binK[NG], binE[NG], binZ[NG], binC[NG];
    const int tid = threadIdx.x;
    for (int i = tid; i < NG; i += 256) { binK[i] = 0.f; binE[i] = 0.f; binZ[i] = 0.f; binC[i] = 0.f; }
    __syncthreads();

    const int CHUNK = 98;
    int start = blockIdx.x * CHUNK;
    int end = min(start + CHUNK, NN);
    int sub = tid >> 5;
    int l32 = tid & 31;
    float bnb0 = bnb[0];

    float4 w1 = ((const float4*)We)[l32];
    float4 w2 = ((const float4*)(We + D))[l32];
    float4 wn = ((const float4*)Wn)[l32];
    float4 bb = ((const float4*)bh1)[l32];

    for (int n = start + sub; n < end; n += 8) {
        uint2 pk = ((const uint2*)(h + (size_t)n * D))[l32];
        float v0 = bf_lo(pk.x) + bb.x;
        float v1 = bf_hi(pk.x) + bb.y;
        float v2 = bf_lo(pk.y) + bb.z;
        float v3 = bf_hi(pk.y) + bb.w;
        float s1 = v0 * w1.x + v1 * w1.y + v2 * w1.z + v3 * w1.w;
        float s2 = v0 * w2.x + v1 * w2.y + v2 * w2.z + v3 * w2.w;
        float s3 = v0 * wn.x + v1 * wn.y + v2 * wn.z + v3 * wn.w;
        for (int o = 16; o; o >>= 1) {
            s1 += __shfl_xor(s1, o);
            s2 += __shfl_xor(s2, o);
            s3 += __shfl_xor(s3, o);
        }
        if (l32 == 0) {
            float nk = sigmoidf(s3 + bnb0);
            nkey_out[n] = nk;
            int g = batch[n];
            tb[n] = make_float4(s1, s2, __int_as_float(g), 0.f);
            atomicAdd(&binK[g], nk);
            atomicAdd(&binE[g], 1.0f - nk);
            if (nk > 0.f) atomicAdd(&binZ[g], 1.0f);
            atomicAdd(&binC[g], 1.0f);
        }
    }
    __syncthreads();
    if (start < NN) {
        int glo = batch[start];
        int ghi = batch[end - 1];
        for (int g = glo + tid; g <= ghi; g += 256) {
            unsafeAtomicAdd(&accN[g], binK[g]);
            unsafeAtomicAdd(&accN[NG + g], binE[g]);
            unsafeAtomicAdd(&accN[2 * NG + g], binZ[g]);
            unsafeAtomicAdd(&accN[3 * NG + g], binC[g]);
        }
    }
}

// edge head + inlined final reduction; tb packs (t1,t2,batch) -> 2 x 16B gathers/edge
__global__ __launch_bounds__(256) void edge_final(
    const int* __restrict__ ei, const float4* __restrict__ tb,
    const float* __restrict__ be, float* __restrict__ ekey_out,
    float* __restrict__ accE, const float* __restrict__ accN,
    int* __restrict__ ctr, float* __restrict__ out) {
    __shared__ float binK[NG], binE[NG], binZ[NG], binC[NG];
    __shared__ int isLast;
    const int tid = threadIdx.x;
    for (int i = tid; i < NG; i += 256) { binK[i] = 0.f; binE[i] = 0.f; binZ[i] = 0.f; binC[i] = 0.f; }
    __syncthreads();
    float be0 = be[0];
    int stride4 = gridDim.x * 256;
    for (int q = blockIdx.x * 256 + tid; q < NE / 4; q += stride4) {
        int4 r4 = ((const int4*)ei)[q];
        int4 c4 = ((const int4*)(ei + NE))[q];
        float4 tr0 = tb[r4.x], tr1 = tb[r4.y], tr2 = tb[r4.z], tr3 = tb[r4.w];
        float4 tc0 = tb[c4.x], tc1 = tb[c4.y], tc2 = tb[c4.z], tc3 = tb[c4.w];
        int g0 = __float_as_int(tr0.z), g1 = __float_as_int(tr1.z);
        int g2 = __float_as_int(tr2.z), g3 = __float_as_int(tr3.z);
        float e0 = sigmoidf(tr0.x + tc0.y + be0);
        float e1 = sigmoidf(tr1.x + tc1.y + be0);
        float e2 = sigmoidf(tr2.x + tc2.y + be0);
        float e3 = sigmoidf(tr3.x + tc3.y + be0);
        ((float4*)ekey_out)[q] = make_float4(e0, e1, e2, e3);
        atomicAdd(&binK[g0], e0); atomicAdd(&binE[g0], 1.0f - e0);
        if (e0 > 0.f) atomicAdd(&binZ[g0], 1.0f);
        atomicAdd(&binC[g0], 1.0f);
        atomicAdd(&binK[g1], e1); atomicAdd(&binE[g1], 1.0f - e1);
        if (e1 > 0.f) atomicAdd(&binZ[g1], 1.0f);
        atomicAdd(&binC[g1], 1.0f);
        atomicAdd(&binK[g2], e2); atomicAdd(&binE[g2], 1.0f - e2);
        if (e2 > 0.f) atomicAdd(&binZ[g2], 1.0f);
        atomicAdd(&binC[g2], 1.0f);
        atomicAdd(&binK[g3], e3); atomicAdd(&binE[g3], 1.0f - e3);
        if (e3 > 0.f) atomicAdd(&binZ[g3], 1.0f);
        atomicAdd(&binC[g3], 1.0f);
    }
    __syncthreads();
    for (int g = tid; g < NG; g += 256) {
        if (binC[g] != 0.f) {
            unsafeAtomicAdd(&accE[g], binK[g]);
            unsafeAtomicAdd(&accE[NG + g], binE[g]);
            unsafeAtomicAdd(&accE[2 * NG + g], binZ[g]);
            unsafeAtomicAdd(&accE[3 * NG + g], binC[g]);
        }
    }
    __syncthreads();
    if (tid == 0) {
        __threadfence();
        int old = atomicAdd(ctr, 1);
        isLast = (old == (int)gridDim.x - 1);
    }
    __syncthreads();
    if (isLast) {
        __threadfence();
        for (int g = tid; g < NG; g += 256) {
            out[O_NKN + g] = accN[g] + 1e-8f;
            out[O_NEN + g] = accN[NG + g] + 1e-8f;
            out[O_EKN + g] = accE[g] + 1e-8f;
            out[O_EEN + g] = accE[NG + g] + 1e-8f;
            out[O_NZN + g] = accN[2 * NG + g] / accN[3 * NG + g];
            out[O_NZE + g] = accE[2 * NG + g] / accE[3 * NG + g];
        }
    }
}

extern "C" void kernel_launch(void* const* d_in, const int* in_sizes, int n_in,
                              void* d_out, int out_size, void* d_ws, size_t ws_size,
                              hipStream_t stream) {
    const float* x     = (const float*)d_in[0];
    const int*   ei    = (const int*)d_in[1];
    const int*   batch = (const int*)d_in[2];
    const float* W     = (const float*)d_in[4];
    const float* bh    = (const float*)d_in[5];   // [2][128]
    const float* gamma = (const float*)d_in[6];
    const float* beta  = (const float*)d_in[7];
    const float* mean  = (const float*)d_in[8];
    const float* var   = (const float*)d_in[9];
    const float* We    = (const float*)d_in[10];
    const float* be    = (const float*)d_in[11];
    const float* Wn    = (const float*)d_in[12];
    const float* bnb   = (const float*)d_in[13];

    float* ws  = (float*)d_ws;
    float* out = (float*)d_out;

    float*        accN  = ws + OFF_ACCN;
    float*        accE  = ws + OFF_ACCE;
    int*          ctr   = (int*)(ws + OFF_CTR);
    float*        dis   = ws + OFF_DIS;
    int*          cnt   = (int*)(ws + OFF_CNT);
    int*          colp  = (int*)(ws + OFF_COLP);
    int*          ends  = (int*)(ws + OFF_ENDS);
    int*          bsum  = (int*)(ws + OFF_BSUM);
    int*          colpL = (int*)(ws + OFF_COLPL);
    float*        bp    = ws + OFF_BP;
    bf16_t*       Wpt   = (bf16_t*)(ws + OFF_WPT);
    int*          PR    = (int*)(ws + OFF_PR);
    int*          PC    = (int*)(ws + OFF_PC);
    unsigned int* srcs  = (unsigned int*)(ws + OFF_SRCS);  // aliases PR
    float4*       tb    = (float4*)(ws + OFF_TB);          // after srcs, PR region
    bf16_t*       hbfA  = (bf16_t*)(ws + OFF_HBFA);
    bf16_t*       hbfB  = (bf16_t*)(ws + OFF_HBFB);

    // CSR count + prep_w + workspace zeroing (merged; no memset dispatch)
    count_prep<<<dim3(2, NCHUNK, 3), 256, RSZC * sizeof(int), stream>>>(
        ei, PR, PC, W, gamma, beta, mean, var, Wpt, bp, ws);
    csr_mid<<<NB, 256, 0, stream>>>(PR, PC, dis, cnt, colpL, bsum);

    const int GB = (NN + 63) / 64;  // 782
    // MERGED: scan (196) || fill (256) || GEMM 0+1 (782); dyn LDS = 51 KB -> 3 blk/CU
    fill_gemm01<<<NB + 256 + GB, 256, 51024, stream>>>(
        ei, colpL, bsum, cnt, colp, ends, PC, dis, srcs,
        x, Wpt, Wpt + D * D, bp, bp + D, hbfB);
    // propagate 1 + fused relu(v + bh0): hbfA = bf16(relu(P(hbfB) + bh0))
    prop_gather<0><<<12500, 256, 0, stream>>>(colp, ends, srcs, dis, hbfB, hbfA, bh);
    // layer 2 linear: hbfB = bf16(hbfA @ Wp2 + bp2)
    gemm2<<<GB, 256, 0, stream>>>(hbfA, Wpt + 2 * D * D, bp + 2 * D, hbfB);
    // propagate 2: hbfA = bf16(P(hbfB))  (node_rep)
    prop_gather<1><<<12500, 256, 0, stream>>>(colp, ends, srcs, dis, hbfB, hbfA, nullptr);

    node_kernel<<<512, 256, 0, stream>>>(hbfA, bh + D, We, Wn, bnb, batch,
                                         out + O_NKEY, tb, accN);
    edge_final<<<EDGE_BLOCKS, 256, 0, stream>>>(ei, tb, be, out + O_EKEY,
                                                accE, accN, ctr, out);
}

// Round 16
// 196.069 us; speedup vs baseline: 1.2858x; 1.0105x over previous
//
#include <hip/hip_runtime.h>
#include <cstddef>
#include <cstring>

#define NN 50000
#define NNP 50048
#define NE 800000
#define D 128
#define NG 512
#define BN_EPS 1e-5f
#define RSZC 25000    // count: nodes per range (2 ranges, 100 KB dyn LDS)
#define RSZF 12500    // fill: nodes per range (4 ranges, 50 KB LDS)
#define NCHUNK 64
#define CSZ 12500     // edges per chunk
#define EDGE_BLOCKS 256
#define NB 196        // csr_mid blocks = ceil(NN/256)

typedef __bf16 bf16_t;
typedef __bf16 bf16x8 __attribute__((ext_vector_type(8)));
typedef float f32x4 __attribute__((ext_vector_type(4)));

// ---- workspace layout (float offsets) ----
#define OFF_ACCN 0            // float[4*512]
#define OFF_ACCE 2048         // float[4*512]
#define OFF_CTR  4096         // int[1]
#define ZERO_FLOATS 4160      // zeroed region = [0, here), zeroed by count_prep
#define OFF_DIS  4160         // float[50048]
#define OFF_COLP 54208       // int[50049] final colp (+1 sentinel)
#define OFF_BSUM 104448      // int[256]
#define OFF_COLPL 104704     // int[50048] block-local exclusive
#define OFF_BP   154752      // float[3*128 padded]
#define OFF_WPT  155264      // bf16[3*128*128] (24576 floats)
#define OFF_PR   179840      // u16[64][50048] = 3203072 u16 = 1601536 floats
#define OFF_PC   1781376     // u16[64][50048] (CPS after csr_mid)
#define OFF_SRCS OFF_PR      // uint[800000], aliases PR (dead after csr_mid)
#define OFF_TB   979840      // float4[50048] = 200192 floats (inside PR region, after srcs)
#define OFF_HBFA 3382912     // bf16[50048*128] (3203072 floats)
#define OFF_HBFB 6585984     // bf16[50048*128]

// ---- output layout (float offsets in d_out) ----
#define O_NKEY 0
#define O_EKEY 50000
#define O_NKN  850000
#define O_NEN  850512
#define O_EKN  851024
#define O_EEN  851536
#define O_NZN  852048
#define O_NZE  852560

__device__ __forceinline__ float sigmoidf(float x) {
    return 1.0f / (1.0f + expf(-x));
}

__device__ __forceinline__ unsigned short f2bf_bits(float f) {
    bf16_t h = (bf16_t)f;
    unsigned short u;
    __builtin_memcpy(&u, &h, 2);
    return u;
}

__device__ __forceinline__ float bf_lo(unsigned int u) {
    return __uint_as_float(u << 16);
}
__device__ __forceinline__ float bf_hi(unsigned int u) {
    return __uint_as_float(u & 0xFFFF0000u);
}

// count histograms (2 ranges x 64 chunks x 2 dirs, u16 output);
// z==2 carries prep_w + workspace zeroing
__global__ __launch_bounds__(256) void count_prep(const int* __restrict__ ei,
                                                  unsigned short* __restrict__ PR,
                                                  unsigned short* __restrict__ PC,
                                                  const float* __restrict__ W,
                                                  const float* __restrict__ gamma,
                                                  const float* __restrict__ beta,
                                                  const float* __restrict__ mean,
                                                  const float* __restrict__ var,
                                                  bf16_t* __restrict__ Wpt,
                                                  float* __restrict__ bp,
                                                  float* __restrict__ zbase) {
    const int tid = threadIdx.x;
    if (blockIdx.z == 2) {
        if (blockIdx.x == 0 && blockIdx.y < 3 && tid < D) {
            int l = blockIdx.y;
            int j = tid;
            float acc = 0.f;
            for (int k = 0; k < D; ++k) {
                float a = gamma[l * D + k] * rsqrtf(var[l * D + k] + BN_EPS);
                float c = beta[l * D + k] - mean[l * D + k] * a;
                float w = W[l * D * D + k * D + j];
                Wpt[l * D * D + j * D + k] = (bf16_t)(a * w);
                acc = fmaf(c, w, acc);
            }
            bp[l * D + j] = acc;
        } else if (blockIdx.x == 1 && blockIdx.y == 0) {
            for (int i = tid; i < ZERO_FLOATS; i += 256) zbase[i] = 0.f;
        }
        return;
    }
    extern __shared__ int hist[];
    const int r = blockIdx.x, p = blockIdx.y, dirz = blockIdx.z;
    for (int i = tid; i < RSZC; i += 256) hist[i] = 0;
    __syncthreads();
    const int base = r * RSZC;
    const int4* ids = (const int4*)(ei + dirz * NE + p * CSZ);
    for (int i = tid; i < CSZ / 4; i += 256) {
        int4 v = ids[i];
        int d0 = v.x - base, d1 = v.y - base, d2 = v.z - base, d3 = v.w - base;
        if ((unsigned)d0 < RSZC) atomicAdd(&hist[d0], 1);
        if ((unsigned)d1 < RSZC) atomicAdd(&hist[d1], 1);
        if ((unsigned)d2 < RSZC) atomicAdd(&hist[d2], 1);
        if ((unsigned)d3 < RSZC) atomicAdd(&hist[d3], 1);
    }
    __syncthreads();
    unsigned short* dst = (dirz == 0 ? PR : PC) + p * NNP + base;
    for (int i = tid; i < RSZC; i += 256) dst[i] = (unsigned short)hist[i];
}

// fused: rowsum->dis, colscan (u16 in-place per-chunk offsets), block-local scan.
// Writes colpL (LOCAL exclusive); final colp produced in the next dispatch.
__global__ void csr_mid(const unsigned short* __restrict__ PR,
                        unsigned short* __restrict__ PC,
                        float* __restrict__ dis,
                        int* __restrict__ colpL, int* __restrict__ bsum) {
    __shared__ int s[256];
    int t = threadIdx.x;
    int i = blockIdx.x * 256 + t;
    int run = 0;
    if (i < NN) {
        int dg = 0;
#pragma unroll 8
        for (int k = 0; k < NCHUNK; ++k) dg += PR[k * NNP + i];
        dis[i] = rsqrtf((float)(dg + 1));
        for (int k = 0; k < NCHUNK; ++k) {
            int v = PC[k * NNP + i];
            PC[k * NNP + i] = (unsigned short)run;
            run += v;
        }
    }
    s[t] = run;
    __syncthreads();
    for (int o = 1; o < 256; o <<= 1) {
        int add = (t >= o) ? s[t - o] : 0;
        __syncthreads();
        s[t] += add;
        __syncthreads();
    }
    if (i < NN) colpL[i] = s[t] - run;  // local exclusive
    if (t == 255) bsum[blockIdx.x] = s[255];
}

// MERGED heterogeneous dispatch, 3 independent block classes.
//   [0,196):    scan-class -> final colp (+ sentinel colp[NN]=NE)
//   [196,452):  CSR fill   -> srcs
//   [452,1234): fused GEMM layers 0+1 (sequential B staging, 48 KB LDS)
__global__ __launch_bounds__(256) void fill_gemm01(
    const int* __restrict__ ei, const int* __restrict__ colpL,
    const int* __restrict__ bsum, int* __restrict__ colp,
    const unsigned short* __restrict__ CPS, const float* __restrict__ dis,
    unsigned int* __restrict__ srcs,
    const float* __restrict__ X, const bf16_t* __restrict__ Bt0,
    const bf16_t* __restrict__ Bt1, const float* __restrict__ bias0,
    const float* __restrict__ bias1, bf16_t* __restrict__ out) {
    extern __shared__ __align__(16) unsigned short smem[];
    const int bid = blockIdx.x;
    const int tid = threadIdx.x;

    if (bid < NB) {
        // ---- scan-class: colp[i] = colpL[i] + sum(bsum[0..bid)); colp[NN]=NE
        int* s = (int*)smem;
        s[tid] = (tid < bid) ? bsum[tid] : 0;
        __syncthreads();
        for (int o = 128; o; o >>= 1) {
            if (tid < o) s[tid] += s[tid + o];
            __syncthreads();
        }
        int boff = s[0];
        int i = bid * 256 + tid;
        if (i < NN) colp[i] = colpL[i] + boff;
        if (i == NN) colp[NN] = NE;
        return;
    }

    if (bid < NB + 256) {
        // ---- CSR fill: packed entries src|bf16(dis[src])<<16 ----
        int* curs = (int*)smem;          // RSZF ints = 50000 B
        int* pb = curs + RSZF;           // 256 ints: exclusive prefix of bsum
        const int fb = bid - NB;
        const int r = fb & 3, p = fb >> 2;
        const int base = r * RSZF;
        {   // exclusive prefix scan of bsum (196 entries) into pb
            int v = (tid < NB) ? bsum[tid] : 0;
            pb[tid] = v;
            __syncthreads();
            for (int o = 1; o < 256; o <<= 1) {
                int add = (tid >= o) ? pb[tid - o] : 0;
                __syncthreads();
                pb[tid] += add;
                __syncthreads();
            }
            int ex = pb[tid] - v;
            __syncthreads();
            pb[tid] = ex;
            __syncthreads();
        }
        for (int i = tid; i < RSZF; i += 256) {
            int g = base + i;
            curs[i] = colpL[g] + pb[g >> 8] + CPS[p * NNP + g];
        }
        __syncthreads();
        const int4* rows = (const int4*)(ei + p * CSZ);
        const int4* cols = (const int4*)(ei + NE + p * CSZ);
        for (int i = tid; i < CSZ / 4; i += 256) {
            int4 rv = rows[i];
            int4 cv = cols[i];
            int d;
            d = cv.x - base;
            if ((unsigned)d < RSZF)
                srcs[atomicAdd(&curs[d], 1)] =
                    (unsigned int)rv.x | ((unsigned int)f2bf_bits(dis[rv.x]) << 16);
            d = cv.y - base;
            if ((unsigned)d < RSZF)
                srcs[atomicAdd(&curs[d], 1)] =
                    (unsigned int)rv.y | ((unsigned int)f2bf_bits(dis[rv.y]) << 16);
            d = cv.z - base;
            if ((unsigned)d < RSZF)
                srcs[atomicAdd(&curs[d], 1)] =
                    (unsigned int)rv.z | ((unsigned int)f2bf_bits(dis[rv.z]) << 16);
            d = cv.w - base;
            if ((unsigned)d < RSZF)
                srcs[atomicAdd(&curs[d], 1)] =
                    (unsigned int)rv.w | ((unsigned int)f2bf_bits(dis[rv.w]) << 16);
        }
        return;
    }

    // ---- fused GEMM layers 0+1; ONE 32 KB B buffer staged twice + 16 KB As ----
    unsigned short* Bs = smem;              // 32 KB (B0 then B1)
    unsigned short* As = smem + 16384;      // 16 KB (h0)
    const int wv = tid >> 6;
    const int lane = tid & 63;
    const int l15 = lane & 15;
    const int l4 = lane >> 4;
    const int row0 = (bid - NB - 256) * 64;

    // stage B0
    for (int q = tid; q < 2048; q += 256) {
        int r = q >> 4, u = q & 15;
        *(uint4*)&Bs[r * 128 + (u ^ (r & 7)) * 8] = *(const uint4*)(Bt0 + r * D + u * 8);
    }

    bf16x8 afrag[4];
    {
        int r = row0 + wv * 16 + l15;
        int rc = (r < NN) ? r : (NN - 1);
#pragma unroll
        for (int kk = 0; kk < 4; ++kk) {
            int off = rc * D + kk * 32 + l4 * 8;
            float4 f0 = *(const float4*)(X + off);
            float4 f1 = *(const float4*)(X + off + 4);
            bf16x8 a;
            a[0] = (bf16_t)f0.x; a[1] = (bf16_t)f0.y;
            a[2] = (bf16_t)f0.z; a[3] = (bf16_t)f0.w;
            a[4] = (bf16_t)f1.x; a[5] = (bf16_t)f1.y;
            a[6] = (bf16_t)f1.z; a[7] = (bf16_t)f1.w;
            afrag[kk] = a;
        }
    }
    __syncthreads();

    const int rsw = l15 & 7;
    f32x4 acc[8];
#pragma unroll
    for (int n = 0; n < 8; ++n) acc[n] = (f32x4){0.f, 0.f, 0.f, 0.f};
#pragma unroll
    for (int n = 0; n < 8; ++n) {
#pragma unroll
        for (int kk = 0; kk < 4; ++kk) {
            bf16x8 bfrag = *(const bf16x8*)&Bs[(n * 16 + l15) * 128 + ((kk * 4 + l4) ^ rsw) * 8];
            acc[n] = __builtin_amdgcn_mfma_f32_16x16x32_bf16(afrag[kk], bfrag, acc[n], 0, 0, 0);
        }
    }
    // epilogue h0 -> swizzled As
#pragma unroll
    for (int n = 0; n < 8; ++n) {
        int col = n * 16 + l15;
        float bv = bias0[col];
#pragma unroll
        for (int r = 0; r < 4; ++r) {
            int rl = wv * 16 + l4 * 4 + r;
            float v = fmaxf(acc[n][r] + bv, 0.f);
            int cs = ((col >> 3) ^ (rl & 7));
            As[rl * 128 + cs * 8 + (col & 7)] = f2bf_bits(v);
        }
    }
    __syncthreads();   // all Bs(B0) reads + As writes complete

    // restage Bs with B1; read h0 fragments from As concurrently
    for (int q = tid; q < 2048; q += 256) {
        int r = q >> 4, u = q & 15;
        *(uint4*)&Bs[r * 128 + (u ^ (r & 7)) * 8] = *(const uint4*)(Bt1 + r * D + u * 8);
    }
    const int rl = wv * 16 + l15;
    bf16x8 af2[4];
#pragma unroll
    for (int kk = 0; kk < 4; ++kk) {
        int cs = (kk * 4 + l4) ^ (rl & 7);
        af2[kk] = *(const bf16x8*)&As[rl * 128 + cs * 8];
    }
    __syncthreads();   // Bs(B1) staged

#pragma unroll
    for (int n = 0; n < 8; ++n) acc[n] = (f32x4){0.f, 0.f, 0.f, 0.f};
#pragma unroll
    for (int n = 0; n < 8; ++n) {
#pragma unroll
        for (int kk = 0; kk < 4; ++kk) {
            bf16x8 bfrag = *(const bf16x8*)&Bs[(n * 16 + l15) * 128 + ((kk * 4 + l4) ^ rsw) * 8];
            acc[n] = __builtin_amdgcn_mfma_f32_16x16x32_bf16(af2[kk], bfrag, acc[n], 0, 0, 0);
        }
    }
#pragma unroll
    for (int n = 0; n < 8; ++n) {
        int col = n * 16 + l15;
        float bv = bias1[col];
#pragma unroll
        for (int r = 0; r < 4; ++r) {
            int row = row0 + wv * 16 + l4 * 4 + r;
            if (row < NN) out[(size_t)row * D + col] = (bf16_t)(acc[n][r] + bv);
        }
    }
}

// layer-2 GEMM with B staged in LDS
__global__ __launch_bounds__(256) void gemm2(const bf16_t* __restrict__ A,
                                             const bf16_t* __restrict__ Bt,
                                             const float* __restrict__ bias,
                                             bf16_t* __restrict__ out) {
    __shared__ __align__(16) unsigned short Bs[128 * 128];
    const int tid = threadIdx.x;
    const int wv = tid >> 6;
    const int lane = tid & 63;
    const int l15 = lane & 15;
    const int l4 = lane >> 4;
    const int row0 = blockIdx.x * 64 + wv * 16;

    for (int q = tid; q < 2048; q += 256) {
        int r = q >> 4, u = q & 15;
        *(uint4*)&Bs[r * 128 + (u ^ (r & 7)) * 8] = *(const uint4*)(Bt + r * D + u * 8);
    }

    bf16x8 afrag[4];
    {
        int r = row0 + l15;
        int rc = (r < NN) ? r : (NN - 1);
#pragma unroll
        for (int kk = 0; kk < 4; ++kk)
            afrag[kk] = *(const bf16x8*)(A + rc * D + kk * 32 + l4 * 8);
    }
    __syncthreads();

    const int rsw = l15 & 7;
    f32x4 acc[8];
#pragma unroll
    for (int n = 0; n < 8; ++n) acc[n] = (f32x4){0.f, 0.f, 0.f, 0.f};
#pragma unroll
    for (int n = 0; n < 8; ++n) {
#pragma unroll
        for (int kk = 0; kk < 4; ++kk) {
            bf16x8 bfrag = *(const bf16x8*)&Bs[(n * 16 + l15) * 128 + ((kk * 4 + l4) ^ rsw) * 8];
            acc[n] = __builtin_amdgcn_mfma_f32_16x16x32_bf16(afrag[kk], bfrag, acc[n], 0, 0, 0);
        }
    }
#pragma unroll
    for (int n = 0; n < 8; ++n) {
        int col = n * 16 + l15;
        float bv = bias[col];
#pragma unroll
        for (int r = 0; r < 4; ++r) {
            int row = row0 + l4 * 4 + r;
            if (row < NN) out[(size_t)row * D + col] = (bf16_t)(acc[n][r] + bv);
        }
    }
}

// gather propagate: one wave per node, unroll x4, packed srcs; end = colp[n+1].
// POST 0: out bf16 = relu(v + bias);  POST 1: out bf16 = v
template <int POST>
__global__ __launch_bounds__(256) void prop_gather(
    const int* __restrict__ colp,
    const unsigned int* __restrict__ srcs, const float* __restrict__ dis,
    const bf16_t* __restrict__ hin, bf16_t* __restrict__ hout,
    const float* __restrict__ bias) {
    int n = blockIdx.x * 4 + (threadIdx.x >> 6);
    n = __builtin_amdgcn_readfirstlane(n);   // wave-uniform: scalarize CSR chain
    int lane = threadIdx.x & 63;
    if (n >= NN) return;
    const int start = colp[n];
    const int end = colp[n + 1];
    const float dn = dis[n];
    unsigned int u = ((const unsigned int*)(hin + (size_t)n * D))[lane];
    float ax = dn * bf_lo(u), ay = dn * bf_hi(u);
    int i = start;
    for (; i + 3 < end; i += 4) {
        unsigned int e0 = srcs[i], e1 = srcs[i + 1], e2 = srcs[i + 2], e3 = srcs[i + 3];
        unsigned int u0 = ((const unsigned int*)(hin + (size_t)(e0 & 0xFFFFu) * D))[lane];
        unsigned int u1 = ((const unsigned int*)(hin + (size_t)(e1 & 0xFFFFu) * D))[lane];
        unsigned int u2 = ((const unsigned int*)(hin + (size_t)(e2 & 0xFFFFu) * D))[lane];
        unsigned int u3 = ((const unsigned int*)(hin + (size_t)(e3 & 0xFFFFu) * D))[lane];
        float w0 = bf_hi(e0), w1 = bf_hi(e1), w2 = bf_hi(e2), w3 = bf_hi(e3);
        ax = fmaf(w0, bf_lo(u0), ax); ay = fmaf(w0, bf_hi(u0), ay);
        ax = fmaf(w1, bf_lo(u1), ax); ay = fmaf(w1, bf_hi(u1), ay);
        ax = fmaf(w2, bf_lo(u2), ax); ay = fmaf(w2, bf_hi(u2), ay);
        ax = fmaf(w3, bf_lo(u3), ax); ay = fmaf(w3, bf_hi(u3), ay);
    }
    for (; i < end; ++i) {
        unsigned int e0 = srcs[i];
        unsigned int u0 = ((const unsigned int*)(hin + (size_t)(e0 & 0xFFFFu) * D))[lane];
        float w0 = bf_hi(e0);
        ax = fmaf(w0, bf_lo(u0), ax); ay = fmaf(w0, bf_hi(u0), ay);
    }
    float vx = dn * ax, vy = dn * ay;
    if (POST == 0) {
        float2 bb = ((const float2*)bias)[lane];
        vx = fmaxf(vx + bb.x, 0.f);
        vy = fmaxf(vy + bb.y, 0.f);
    }
    unsigned int pk = (unsigned int)f2bf_bits(vx) | ((unsigned int)f2bf_bits(vy) << 16);
    ((unsigned int*)(hout + (size_t)n * D))[lane] = pk;
}

// node head on bf16 node_rep; writes packed tb = (t1, t2, batch, 0) per node
__global__ __launch_bounds__(256) void node_kernel(
    const bf16_t* __restrict__ h, const float* __restrict__ bh1,
    const float* __restrict__ We, const float* __restrict__ Wn,
    const float* __restrict__ bnb, const int* __restrict__ batch,
    float* __restrict__ nkey_out, float4* __restrict__ tb,
    float* __restrict__ accN) {
    __shared__ float binK[NG], binE[NG], binZ[NG], binC[NG];
    const int tid = threadIdx.x;
    for (int i = tid; i < NG; i += 256) { binK[i] = 0.f; binE[i] = 0.f; binZ[i] = 0.f; binC[i] = 0.f; }
    __syncthreads();

    const int CHUNK = 98;
    int start = blockIdx.x * CHUNK;
    int end = min(start + CHUNK, NN);
    int sub = tid >> 5;
    int l32 = tid & 31;
    float bnb0 = bnb[0];

    float4 w1 = ((const float4*)We)[l32];
    float4 w2 = ((const float4*)(We + D))[l32];
    float4 wn = ((const float4*)Wn)[l32];
    float4 bb = ((const float4*)bh1)[l32];

    for (int n = start + sub; n < end; n += 8) {
        uint2 pk = ((const uint2*)(h + (size_t)n * D))[l32];
        float v0 = bf_lo(pk.x) + bb.x;
        float v1 = bf_hi(pk.x) + bb.y;
        float v2 = bf_lo(pk.y) + bb.z;
        float v3 = bf_hi(pk.y) + bb.w;
        float s1 = v0 * w1.x + v1 * w1.y + v2 * w1.z + v3 * w1.w;
        float s2 = v0 * w2.x + v1 * w2.y + v2 * w2.z + v3 * w2.w;
        float s3 = v0 * wn.x + v1 * wn.y + v2 * wn.z + v3 * wn.w;
        for (int o = 16; o; o >>= 1) {
            s1 += __shfl_xor(s1, o);
            s2 += __shfl_xor(s2, o);
            s3 += __shfl_xor(s3, o);
        }
        if (l32 == 0) {
            float nk = sigmoidf(s3 + bnb0);
            nkey_out[n] = nk;
            int g = batch[n];
            tb[n] = make_float4(s1, s2, __int_as_float(g), 0.f);
            atomicAdd(&binK[g], nk);
            atomicAdd(&binE[g], 1.0f - nk);
            if (nk > 0.f) atomicAdd(&binZ[g], 1.0f);
            atomicAdd(&binC[g], 1.0f);
        }
    }
    __syncthreads();
    if (start < NN) {
        int glo = batch[start];
        int ghi = batch[end - 1];
        for (int g = glo + tid; g <= ghi; g += 256) {
            unsafeAtomicAdd(&accN[g], binK[g]);
            unsafeAtomicAdd(&accN[NG + g], binE[g]);
            unsafeAtomicAdd(&accN[2 * NG + g], binZ[g]);
            unsafeAtomicAdd(&accN[3 * NG + g], binC[g]);
        }
    }
}

// edge head + inlined final reduction; tb packs (t1,t2,batch) -> 2 x 16B gathers/edge
__global__ __launch_bounds__(256) void edge_final(
    const int* __restrict__ ei, const float4* __restrict__ tb,
    const float* __restrict__ be, float* __restrict__ ekey_out,
    float* __restrict__ accE, const float* __restrict__ accN,
    int* __restrict__ ctr, float* __restrict__ out) {
    __shared__ float binK[NG], binE[NG], binZ[NG], binC[NG];
    __shared__ int isLast;
    const int tid = threadIdx.x;
    for (int i = tid; i < NG; i += 256) { binK[i] = 0.f; binE[i] = 0.f; binZ[i] = 0.f; binC[i] = 0.f; }
    __syncthreads();
    float be0 = be[0];
    int stride4 = gridDim.x * 256;
    for (int q = blockIdx.x * 256 + tid; q < NE / 4; q += stride4) {
        int4 r4 = ((const int4*)ei)[q];
        int4 c4 = ((const int4*)(ei + NE))[q];
        float4 tr0 = tb[r4.x], tr1 = tb[r4.y], tr2 = tb[r4.z], tr3 = tb[r4.w];
        float4 tc0 = tb[c4.x], tc1 = tb[c4.y], tc2 = tb[c4.z], tc3 = tb[c4.w];
        int g0 = __float_as_int(tr0.z), g1 = __float_as_int(tr1.z);
        int g2 = __float_as_int(tr2.z), g3 = __float_as_int(tr3.z);
        float e0 = sigmoidf(tr0.x + tc0.y + be0);
        float e1 = sigmoidf(tr1.x + tc1.y + be0);
        float e2 = sigmoidf(tr2.x + tc2.y + be0);
        float e3 = sigmoidf(tr3.x + tc3.y + be0);
        ((float4*)ekey_out)[q] = make_float4(e0, e1, e2, e3);
        atomicAdd(&binK[g0], e0); atomicAdd(&binE[g0], 1.0f - e0);
        if (e0 > 0.f) atomicAdd(&binZ[g0], 1.0f);
        atomicAdd(&binC[g0], 1.0f);
        atomicAdd(&binK[g1], e1); atomicAdd(&binE[g1], 1.0f - e1);
        if (e1 > 0.f) atomicAdd(&binZ[g1], 1.0f);
        atomicAdd(&binC[g1], 1.0f);
        atomicAdd(&binK[g2], e2); atomicAdd(&binE[g2], 1.0f - e2);
        if (e2 > 0.f) atomicAdd(&binZ[g2], 1.0f);
        atomicAdd(&binC[g2], 1.0f);
        atomicAdd(&binK[g3], e3); atomicAdd(&binE[g3], 1.0f - e3);
        if (e3 > 0.f) atomicAdd(&binZ[g3], 1.0f);
        atomicAdd(&binC[g3], 1.0f);
    }
    __syncthreads();
    for (int g = tid; g < NG; g += 256) {
        if (binC[g] != 0.f) {
            unsafeAtomicAdd(&accE[g], binK[g]);
            unsafeAtomicAdd(&accE[NG + g], binE[g]);
            unsafeAtomicAdd(&accE[2 * NG + g], binZ[g]);
            unsafeAtomicAdd(&accE[3 * NG + g], binC[g]);
        }
    }
    __syncthreads();
    if (tid == 0) {
        __threadfence();
        int old = atomicAdd(ctr, 1);
        isLast = (old == (int)gridDim.x - 1);
    }
    __syncthreads();
    if (isLast) {
        __threadfence();
        for (int g = tid; g < NG; g += 256) {
            out[O_NKN + g] = accN[g] + 1e-8f;
            out[O_NEN + g] = accN[NG + g] + 1e-8f;
            out[O_EKN + g] = accE[g] + 1e-8f;
            out[O_EEN + g] = accE[NG + g] + 1e-8f;
            out[O_NZN + g] = accN[2 * NG + g] / accN[3 * NG + g];
            out[O_NZE + g] = accE[2 * NG + g] / accE[3 * NG + g];
        }
    }
}

extern "C" void kernel_launch(void* const* d_in, const int* in_sizes, int n_in,
                              void* d_out, int out_size, void* d_ws, size_t ws_size,
                              hipStream_t stream) {
    const float* x     = (const float*)d_in[0];
    const int*   ei    = (const int*)d_in[1];
    const int*   batch = (const int*)d_in[2];
    const float* W     = (const float*)d_in[4];
    const float* bh    = (const float*)d_in[5];   // [2][128]
    const float* gamma = (const float*)d_in[6];
    const float* beta  = (const float*)d_in[7];
    const float* mean  = (const float*)d_in[8];
    const float* var   = (const float*)d_in[9];
    const float* We    = (const float*)d_in[10];
    const float* be    = (const float*)d_in[11];
    const float* Wn    = (const float*)d_in[12];
    const float* bnb   = (const float*)d_in[13];

    float* ws  = (float*)d_ws;
    float* out = (float*)d_out;

    float*          accN  = ws + OFF_ACCN;
    float*          accE  = ws + OFF_ACCE;
    int*            ctr   = (int*)(ws + OFF_CTR);
    float*          dis   = ws + OFF_DIS;
    int*            colp  = (int*)(ws + OFF_COLP);
    int*            bsum  = (int*)(ws + OFF_BSUM);
    int*            colpL = (int*)(ws + OFF_COLPL);
    float*          bp    = ws + OFF_BP;
    bf16_t*         Wpt   = (bf16_t*)(ws + OFF_WPT);
    unsigned short* PR    = (unsigned short*)(ws + OFF_PR);
    unsigned short* PC    = (unsigned short*)(ws + OFF_PC);
    unsigned int*   srcs  = (unsigned int*)(ws + OFF_SRCS);  // aliases PR
    float4*         tb    = (float4*)(ws + OFF_TB);          // after srcs, PR region
    bf16_t*         hbfA  = (bf16_t*)(ws + OFF_HBFA);
    bf16_t*         hbfB  = (bf16_t*)(ws + OFF_HBFB);

    // CSR count + prep_w + workspace zeroing (merged; no memset dispatch)
    count_prep<<<dim3(2, NCHUNK, 3), 256, RSZC * sizeof(int), stream>>>(
        ei, PR, PC, W, gamma, beta, mean, var, Wpt, bp, ws);
    csr_mid<<<NB, 256, 0, stream>>>(PR, PC, dis, colpL, bsum);

    const int GB = (NN + 63) / 64;  // 782
    // MERGED: scan (196) || fill (256) || GEMM 0+1 (782); dyn LDS = 51 KB -> 3 blk/CU
    fill_gemm01<<<NB + 256 + GB, 256, 51024, stream>>>(
        ei, colpL, bsum, colp, PC, dis, srcs,
        x, Wpt, Wpt + D * D, bp, bp + D, hbfB);
    // propagate 1 + fused relu(v + bh0): hbfA = bf16(relu(P(hbfB) + bh0))
    prop_gather<0><<<12500, 256, 0, stream>>>(colp, srcs, dis, hbfB, hbfA, bh);
    // layer 2 linear: hbfB = bf16(hbfA @ Wp2 + bp2)
    gemm2<<<GB, 256, 0, stream>>>(hbfA, Wpt + 2 * D * D, bp + 2 * D, hbfB);
    // propagate 2: hbfA = bf16(P(hbfB))  (node_rep)
    prop_gather<1><<<12500, 256, 0, stream>>>(colp, srcs, dis, hbfB, hbfA, nullptr);

    node_kernel<<<512, 256, 0, stream>>>(hbfA, bh + D, We, Wn, bnb, batch,
                                         out + O_NKEY, tb, accN);
    edge_final<<<EDGE_BLOCKS, 256, 0, stream>>>(ei, tb, be, out + O_EKEY,
                                                accE, accN, ctr, out);
}